// Round 8
// baseline (314.160 us; speedup 1.0000x reference)
//
#include <hip/hip_runtime.h>
#include <hip/hip_fp16.h>
#include <math.h>

#define N_GRAPHS 256
#define F_IN 12
#define XS_STRIDE 16
#define HID 64
#define FC_DIM 140
#define NPART 8     // edge-binning partitions (blockIdx & 7; XCD-affine if round-robin)
#define PCAP 224    // per-(bucket,partition) capacity: mean 128, sd ~11 -> +8.5 sigma
#define SCAP (NPART * PCAP)  // 1792: sorted-bucket stride / max edges per bucket
#define EPT 7       // SCAP / 256

__device__ __forceinline__ float bcast_lane(float v, int k) {
    return __uint_as_float(__builtin_amdgcn_readlane(__float_as_uint(v), k));
}

// ---------- bucket binning: bucket = dst>>6, partition = blockIdx&7 ----------
__global__ void count_bin(const int* __restrict__ src, const int* __restrict__ dst, int E,
                          int* __restrict__ bcnt2, int* __restrict__ sedge2) {
    int e = blockIdx.x * blockDim.x + threadIdx.x;
    if (e >= E) return;
    int p = blockIdx.x & (NPART - 1);
    int d = dst[e];
    int b = d >> 6;
    int pos = atomicAdd(&bcnt2[(b * NPART + p) * 16], 1);
    if (pos < PCAP) sedge2[((size_t)b * NPART + p) * PCAP + pos] = src[e] | ((d & 63) << 20);
}

// ---------- per-bucket counting sort (LDS) + degree -> dinv ----------
__global__ __launch_bounds__(256) void bucket_sort(
        const int* __restrict__ bcnt2, const int* __restrict__ sedge2,
        int* __restrict__ sedgeS, int* __restrict__ boff, float* __restrict__ dinv, int N) {
    __shared__ int cnt[64];
    __shared__ int cur[64];
    __shared__ int esl[SCAP];
    __shared__ int pbase[NPART + 1];
    int tid = threadIdx.x, b = blockIdx.x;
    if (tid < 64) cnt[tid] = 0;
    if (tid == 0) {
        int s = 0;
        for (int p = 0; p < NPART; p++) {
            pbase[p] = s;
            s += min(bcnt2[(b * NPART + p) * 16], PCAP);
        }
        pbase[NPART] = s;
    }
    __syncthreads();
    int ne = pbase[NPART];
    int ed[EPT], dl[EPT];
#pragma unroll
    for (int k = 0; k < EPT; k++) {
        int idx = tid + k * 256;
        int v = -1;
        if (idx < ne) {
            int p = 0;
#pragma unroll
            for (int q = 1; q < NPART; q++) p += (idx >= pbase[q]);
            v = sedge2[((size_t)b * NPART + p) * PCAP + (idx - pbase[p])];
        }
        ed[k] = v;
        dl[k] = (v >> 20) & 63;
        if (v >= 0) atomicAdd(&cnt[dl[k]], 1);
    }
    __syncthreads();
    if (tid < 64) {
        int c = cnt[tid];
        int incl = c;
#pragma unroll
        for (int off = 1; off < 64; off <<= 1) {
            int t = __shfl_up(incl, off, 64);
            if (tid >= off) incl += t;
        }
        cur[tid] = incl - c;
        boff[b * 65 + tid] = incl - c;
        if (tid == 63) boff[b * 65 + 64] = incl;
        int node = b * 64 + tid;
        if (node < N) dinv[node] = rsqrtf((float)(c + 1));  // +1 self-loop
    }
    __syncthreads();
#pragma unroll
    for (int k = 0; k < EPT; k++) {
        if (ed[k] >= 0) {
            int pos = atomicAdd(&cur[dl[k]], 1);
            esl[pos] = ed[k] & 0xFFFFF;   // src only; dlow implicit in position
        }
    }
    __syncthreads();
    for (int idx = tid; idx < ne; idx += 256) sedgeS[(size_t)b * SCAP + idx] = esl[idx];
}

// ---------- prescaled half x table (16-half rows, 32 B) ----------
__global__ void make_xs(const float* __restrict__ dinv, const float* __restrict__ x,
                        __half* __restrict__ xs, int N) {
    int t = blockIdx.x * blockDim.x + threadIdx.x;
    int node = t >> 4, f = t & 15;
    if (node >= N) return;
    float v = (f < F_IN) ? dinv[node] * x[node * F_IN + f] : 0.f;
    xs[node * XS_STRIDE + f] = __float2half(v);
}

// ---------- fused layer-1: scalar edge walk + gather + mm1 + tanh ----------
// One wave per node; edge indices via SMEM (wave-uniform), 16-lane ushort gathers.
__global__ __launch_bounds__(256) void agg_x_mm1(
        const __half* __restrict__ xs, const float* __restrict__ dinv,
        const int* __restrict__ boff, const int* __restrict__ sedgeS,
        const float* __restrict__ W1, const float* __restrict__ b1,
        __half* __restrict__ h1h, __half* __restrict__ h1s, int N) {
    int tid = threadIdx.x, wv = tid >> 6, lane = tid & 63;
    float w1c[F_IN];
#pragma unroll
    for (int k = 0; k < F_IN; k++) w1c[k] = W1[k * HID + lane];  // coalesced
    float bias = b1[lane];
    int node = blockIdx.x * 4 + wv;
    if (node >= N) return;
    int nu = __builtin_amdgcn_readfirstlane(node);
    int bu = nu >> 6, dl = nu & 63;
    int p0 = boff[bu * 65 + dl], p1 = boff[bu * 65 + dl + 1];
    const int* ep = sedgeS + (size_t)bu * SCAP;
    bool act = lane < XS_STRIDE;
    float acc = 0.f;
    int i = p0;
    for (; i + 8 <= p1; i += 8) {
        int j0 = ep[i + 0], j1 = ep[i + 1], j2 = ep[i + 2], j3 = ep[i + 3];
        int j4 = ep[i + 4], j5 = ep[i + 5], j6 = ep[i + 6], j7 = ep[i + 7];
        if (act) {
            float v0 = __half2float(xs[j0 * XS_STRIDE + lane]);
            float v1 = __half2float(xs[j1 * XS_STRIDE + lane]);
            float v2 = __half2float(xs[j2 * XS_STRIDE + lane]);
            float v3 = __half2float(xs[j3 * XS_STRIDE + lane]);
            float v4 = __half2float(xs[j4 * XS_STRIDE + lane]);
            float v5 = __half2float(xs[j5 * XS_STRIDE + lane]);
            float v6 = __half2float(xs[j6 * XS_STRIDE + lane]);
            float v7 = __half2float(xs[j7 * XS_STRIDE + lane]);
            acc += ((v0 + v1) + (v2 + v3)) + ((v4 + v5) + (v6 + v7));
        }
    }
    for (; i < p1; ++i) {
        int j = ep[i];
        if (act) acc += __half2float(xs[j * XS_STRIDE + lane]);
    }
    float di = dinv[nu];
    if (act) acc = di * (acc + __half2float(xs[nu * XS_STRIDE + lane]));  // self-loop
    float o = bias;
#pragma unroll
    for (int k = 0; k < F_IN; k++) o += bcast_lane(acc, k) * w1c[k];
    float v = tanhf(o);
    h1h[(size_t)nu * HID + lane] = __float2half(v);
    h1s[(size_t)nu * HID + lane] = __float2half(di * v);
}

// ---------- fused layer-2: scalar edge walk + full-wave gather + mm2 + tanh ----------
#define NPB 16   // nodes per block (4 per wave)
__global__ __launch_bounds__(256) void agg_h_mm2(
        const __half* __restrict__ h1s, const float* __restrict__ dinv,
        const int* __restrict__ boff, const int* __restrict__ sedgeS,
        const float* __restrict__ W2, const float* __restrict__ b2,
        __half* __restrict__ h2, int N) {
    __shared__ float wT[HID * 68];     // transposed W2, padded: wT[f*68+k] = W2[k][f]
    int tid = threadIdx.x, wv = tid >> 6, lane = tid & 63;
    for (int i = tid; i < HID * HID; i += 256) {
        int k = i >> 6, f = i & 63;
        wT[f * 68 + k] = W2[i];        // read coalesced
    }
    float bias = b2[lane];
    __syncthreads();
    int node0 = blockIdx.x * NPB + wv * 4;
    for (int q = 0; q < 4; ++q) {
        int node = node0 + q;
        if (node >= N) break;
        int nu = __builtin_amdgcn_readfirstlane(node);
        int bu = nu >> 6, dl = nu & 63;
        int p0 = boff[bu * 65 + dl], p1 = boff[bu * 65 + dl + 1];
        const int* ep = sedgeS + (size_t)bu * SCAP;
        float acc = 0.f;
        int i = p0;
        for (; i + 8 <= p1; i += 8) {
            int j0 = ep[i + 0], j1 = ep[i + 1], j2 = ep[i + 2], j3 = ep[i + 3];
            int j4 = ep[i + 4], j5 = ep[i + 5], j6 = ep[i + 6], j7 = ep[i + 7];
            float v0 = __half2float(h1s[(size_t)j0 * HID + lane]);
            float v1 = __half2float(h1s[(size_t)j1 * HID + lane]);
            float v2 = __half2float(h1s[(size_t)j2 * HID + lane]);
            float v3 = __half2float(h1s[(size_t)j3 * HID + lane]);
            float v4 = __half2float(h1s[(size_t)j4 * HID + lane]);
            float v5 = __half2float(h1s[(size_t)j5 * HID + lane]);
            float v6 = __half2float(h1s[(size_t)j6 * HID + lane]);
            float v7 = __half2float(h1s[(size_t)j7 * HID + lane]);
            acc += ((v0 + v1) + (v2 + v3)) + ((v4 + v5) + (v6 + v7));
        }
        for (; i < p1; ++i) {
            int j = ep[i];
            acc += __half2float(h1s[(size_t)j * HID + lane]);
        }
        float di = dinv[nu];
        acc += __half2float(h1s[(size_t)nu * HID + lane]);  // self-loop (prescaled)
        float r = di * acc;                                  // lane f holds agg[f]
        float o = bias;
        const float4* wrow = (const float4*)&wT[lane * 68];
#pragma unroll
        for (int k = 0; k < HID; k += 4) {
            float4 w4 = wrow[k >> 2];
            o += bcast_lane(r, k + 0) * w4.x;
            o += bcast_lane(r, k + 1) * w4.y;
            o += bcast_lane(r, k + 2) * w4.z;
            o += bcast_lane(r, k + 3) * w4.w;
        }
        h2[(size_t)nu * HID + lane] = __float2half(tanhf(o));
    }
}

// ---------- pooled[g] = sum over nodes in graph g of [x, h1, h2] ----------
__device__ __forceinline__ int lower_bound_i(const int* b, int n, int v) {
    int lo = 0, hi = n;
    while (lo < hi) { int m = (lo + hi) >> 1; if (b[m] < v) lo = m + 1; else hi = m; }
    return lo;
}

__global__ void pool_kernel(const float* __restrict__ x, const __half* __restrict__ h1h,
                            const __half* __restrict__ h2, const int* __restrict__ batch,
                            float* __restrict__ pooled, int N) {
    int g = blockIdx.x >> 3;
    int sub = blockIdx.x & 7;
    int start = lower_bound_i(batch, N, g);
    int end = lower_bound_i(batch, N, g + 1);
    int len = end - start;
    int per = (len + 7) >> 3;
    int s = start + sub * per;
    int e = min(s + per, end);
    int f = threadIdx.x;
    if (f >= FC_DIM || s >= e) return;
    float acc = 0.f;
    if (f < F_IN) {
        for (int node = s; node < e; ++node) acc += x[node * F_IN + f];
    } else if (f < F_IN + HID) {
        int off = f - F_IN;
        for (int node = s; node < e; ++node) acc += __half2float(h1h[node * HID + off]);
    } else {
        int off = f - F_IN - HID;
        for (int node = s; node < e; ++node) acc += __half2float(h2[node * HID + off]);
    }
    atomicAdd(&pooled[g * FC_DIM + f], acc);
}

// ---------- out = pooled @ fc_W^T + fc_b ----------
__global__ void fc_kernel(const float* __restrict__ pooled, const float* __restrict__ fcW,
                          const float* __restrict__ fcb, float* __restrict__ out) {
    __shared__ float p[FC_DIM];
    int g = blockIdx.x, tid = threadIdx.x;
    if (tid < FC_DIM) p[tid] = pooled[g * FC_DIM + tid];
    __syncthreads();
    if (tid < FC_DIM) {
        float acc = fcb[tid];
        for (int k = 0; k < FC_DIM; k++) acc += p[k] * fcW[tid * FC_DIM + k];
        out[g * FC_DIM + tid] = acc;
    }
}

extern "C" void kernel_launch(void* const* d_in, const int* in_sizes, int n_in,
                              void* d_out, int out_size, void* d_ws, size_t ws_size,
                              hipStream_t stream) {
    const float* x   = (const float*)d_in[0];
    const float* W1  = (const float*)d_in[1];
    const float* b1  = (const float*)d_in[2];
    const float* W2  = (const float*)d_in[3];
    const float* b2  = (const float*)d_in[4];
    const float* fcW = (const float*)d_in[5];
    const float* fcb = (const float*)d_in[6];
    const int*   ei  = (const int*)d_in[7];
    const int*   batch = (const int*)d_in[8];
    const int N = in_sizes[8];
    const int E = in_sizes[7] / 2;
    const int* src = ei;
    const int* dst = ei + E;
    const int NB = (N + 63) / 64;

    char* ws = (char*)d_ws;
    size_t off = 0;
    auto alloc = [&](size_t bytes) -> void* {
        void* p = ws + off; off += (bytes + 255) & ~(size_t)255; return p;
    };
    int*    bcnt2  = (int*)alloc((size_t)NB * NPART * 16 * 4);   // padded cursors
    int*    sedge2 = (int*)alloc((size_t)NB * NPART * PCAP * 4); // partitioned bins
    int*    sedgeS = (int*)alloc((size_t)NB * SCAP * 4);         // sorted buckets
    int*    boff   = (int*)alloc((size_t)NB * 65 * 4);
    float*  dinv   = (float*)alloc((size_t)N * 4);
    __half* xs     = (__half*)alloc((size_t)N * XS_STRIDE * 2);
    __half* h1h    = (__half*)alloc((size_t)N * HID * 2);
    __half* h1s    = (__half*)alloc((size_t)N * HID * 2);
    __half* h2     = (__half*)alloc((size_t)N * HID * 2);
    float*  pooled = (float*)alloc((size_t)N_GRAPHS * FC_DIM * 4);
    float* out = (float*)d_out;

    hipMemsetAsync(bcnt2, 0, (size_t)NB * NPART * 16 * 4, stream);
    hipMemsetAsync(pooled, 0, (size_t)N_GRAPHS * FC_DIM * 4, stream);

    count_bin<<<(E + 255) / 256, 256, 0, stream>>>(src, dst, E, bcnt2, sedge2);
    bucket_sort<<<NB, 256, 0, stream>>>(bcnt2, sedge2, sedgeS, boff, dinv, N);
    make_xs<<<((size_t)N * 16 + 255) / 256, 256, 0, stream>>>(dinv, x, xs, N);
    agg_x_mm1<<<(N + 3) / 4, 256, 0, stream>>>(xs, dinv, boff, sedgeS, W1, b1, h1h, h1s, N);
    agg_h_mm2<<<(N + NPB - 1) / NPB, 256, 0, stream>>>(h1s, dinv, boff, sedgeS,
                                                       W2, b2, h2, N);
    pool_kernel<<<N_GRAPHS * 8, 192, 0, stream>>>(x, h1h, h2, batch, pooled, N);
    fc_kernel<<<N_GRAPHS, 192, 0, stream>>>(pooled, fcW, fcb, out);
}

// Round 9
// 299.760 us; speedup vs baseline: 1.0480x; 1.0480x over previous
//
#include <hip/hip_runtime.h>
#include <hip/hip_fp16.h>
#include <math.h>

#define N_GRAPHS 256
#define F_IN 12
#define XS_STRIDE 16
#define HID 64
#define FC_DIM 140
#define NPART 8     // edge-binning partitions (blockIdx & 7; XCD-affine if round-robin)
#define PCAP 224    // per-(bucket,partition) capacity: mean 128, sd ~11 -> +8.5 sigma
#define SCAP (NPART * PCAP)  // 1792: sorted-bucket stride / max edges per bucket
#define EPT 7       // SCAP / 256

__device__ __forceinline__ float bcast_lane(float v, int k) {
    return __uint_as_float(__builtin_amdgcn_readlane(__float_as_uint(v), k));
}

// ---------- bucket binning: 4 edges/thread, independent atomic chains ----------
__global__ void count_bin(const int* __restrict__ src, const int* __restrict__ dst, int E,
                          int* __restrict__ bcnt2, int* __restrict__ sedge2) {
    int t = blockIdx.x * blockDim.x + threadIdx.x;
    int e0 = t * 4;
    if (e0 >= E) return;
    int p = blockIdx.x & (NPART - 1);
    if (e0 + 4 <= E) {
        int4 d4 = *(const int4*)&dst[e0];
        int4 s4 = *(const int4*)&src[e0];
        int ds[4] = {d4.x, d4.y, d4.z, d4.w};
        int ss[4] = {s4.x, s4.y, s4.z, s4.w};
#pragma unroll
        for (int k = 0; k < 4; k++) {
            int d = ds[k], b = d >> 6;
            int pos = atomicAdd(&bcnt2[(b * NPART + p) * 16], 1);
            if (pos < PCAP) sedge2[((size_t)b * NPART + p) * PCAP + pos] = ss[k] | ((d & 63) << 20);
        }
    } else {
        for (int e = e0; e < E; ++e) {
            int d = dst[e], b = d >> 6;
            int pos = atomicAdd(&bcnt2[(b * NPART + p) * 16], 1);
            if (pos < PCAP) sedge2[((size_t)b * NPART + p) * PCAP + pos] = src[e] | ((d & 63) << 20);
        }
    }
}

// ---------- per-bucket counting sort (LDS) + degree -> dinv ----------
__global__ __launch_bounds__(256) void bucket_sort(
        const int* __restrict__ bcnt2, const int* __restrict__ sedge2,
        int* __restrict__ sedgeS, int* __restrict__ boff, float* __restrict__ dinv, int N) {
    __shared__ int cnt[64];
    __shared__ int cur[64];
    __shared__ int esl[SCAP];
    __shared__ int pbase[NPART + 1];
    int tid = threadIdx.x, b = blockIdx.x;
    if (tid < 64) cnt[tid] = 0;
    if (tid == 0) {
        int s = 0;
        for (int p = 0; p < NPART; p++) {
            pbase[p] = s;
            s += min(bcnt2[(b * NPART + p) * 16], PCAP);
        }
        pbase[NPART] = s;
    }
    __syncthreads();
    int ne = pbase[NPART];
    int ed[EPT], dl[EPT];
#pragma unroll
    for (int k = 0; k < EPT; k++) {
        int idx = tid + k * 256;
        int v = -1;
        if (idx < ne) {
            int p = 0;
#pragma unroll
            for (int q = 1; q < NPART; q++) p += (idx >= pbase[q]);
            v = sedge2[((size_t)b * NPART + p) * PCAP + (idx - pbase[p])];
        }
        ed[k] = v;
        dl[k] = (v >> 20) & 63;
        if (v >= 0) atomicAdd(&cnt[dl[k]], 1);
    }
    __syncthreads();
    if (tid < 64) {
        int c = cnt[tid];
        int incl = c;
#pragma unroll
        for (int off = 1; off < 64; off <<= 1) {
            int t = __shfl_up(incl, off, 64);
            if (tid >= off) incl += t;
        }
        cur[tid] = incl - c;
        boff[b * 65 + tid] = incl - c;
        if (tid == 63) boff[b * 65 + 64] = incl;
        int node = b * 64 + tid;
        if (node < N) dinv[node] = rsqrtf((float)(c + 1));  // +1 self-loop
    }
    __syncthreads();
#pragma unroll
    for (int k = 0; k < EPT; k++) {
        if (ed[k] >= 0) {
            int pos = atomicAdd(&cur[dl[k]], 1);
            esl[pos] = ed[k] & 0xFFFFF;   // src only; dlow implicit in position
        }
    }
    __syncthreads();
    for (int idx = tid; idx < ne; idx += 256) sedgeS[(size_t)b * SCAP + idx] = esl[idx];
}

// ---------- prescaled half x table (16-half rows, 32 B) ----------
__global__ void make_xs(const float* __restrict__ dinv, const float* __restrict__ x,
                        __half* __restrict__ xs, int N) {
    int t = blockIdx.x * blockDim.x + threadIdx.x;
    int node = t >> 4, f = t & 15;
    if (node >= N) return;
    float v = (f < F_IN) ? dinv[node] * x[node * F_IN + f] : 0.f;
    xs[node * XS_STRIDE + f] = __float2half(v);
}

// ---------- fused layer-1: 8-lane half2 gather (8 nodes/wave) + mm1 + tanh -> h1s ----------
__global__ __launch_bounds__(256) void agg_x_mm1(
        const __half2* __restrict__ xs2, const float* __restrict__ dinv,
        const int* __restrict__ boff, const int* __restrict__ sedgeS,
        const float* __restrict__ W1, const float* __restrict__ b1,
        __half* __restrict__ h1s, int N) {
    int tid = threadIdx.x, wv = tid >> 6, lane = tid & 63;
    int c = lane & 7, gb = lane & 56;  // group base within wave
    float w1c[F_IN];
#pragma unroll
    for (int k = 0; k < F_IN; k++) w1c[k] = W1[k * HID + lane];  // coalesced
    float bias = b1[lane];
    int node = blockIdx.x * 32 + (tid >> 3);
    float ax = 0.f, ay = 0.f, di = 0.f;
    if (node < N) {
        int b = node >> 6, dlow = node & 63;
        di = dinv[node];
        int p0 = boff[b * 65 + dlow], p1 = boff[b * 65 + dlow + 1];
        const int* ep = sedgeS + (size_t)b * SCAP;
        for (int base = p0; base < p1; base += 8) {
            int rem = p1 - base;
            int el = (base + c < p1) ? ep[base + c] : 0;
            int j0 = __shfl(el, gb + 0, 64);
            int j1 = __shfl(el, gb + 1, 64);
            int j2 = __shfl(el, gb + 2, 64);
            int j3 = __shfl(el, gb + 3, 64);
            int j4 = __shfl(el, gb + 4, 64);
            int j5 = __shfl(el, gb + 5, 64);
            int j6 = __shfl(el, gb + 6, 64);
            int j7 = __shfl(el, gb + 7, 64);
            float2 v0 = __half22float2(xs2[j0 * 8 + c]);
            float2 v1 = __half22float2(xs2[j1 * 8 + c]);
            float2 v2 = __half22float2(xs2[j2 * 8 + c]);
            float2 v3 = __half22float2(xs2[j3 * 8 + c]);
            float2 v4 = __half22float2(xs2[j4 * 8 + c]);
            float2 v5 = __half22float2(xs2[j5 * 8 + c]);
            float2 v6 = __half22float2(xs2[j6 * 8 + c]);
            float2 v7 = __half22float2(xs2[j7 * 8 + c]);
            if (0 < rem) { ax += v0.x; ay += v0.y; }
            if (1 < rem) { ax += v1.x; ay += v1.y; }
            if (2 < rem) { ax += v2.x; ay += v2.y; }
            if (3 < rem) { ax += v3.x; ay += v3.y; }
            if (4 < rem) { ax += v4.x; ay += v4.y; }
            if (5 < rem) { ax += v5.x; ay += v5.y; }
            if (6 < rem) { ax += v6.x; ay += v6.y; }
            if (7 < rem) { ax += v7.x; ay += v7.y; }
        }
        float2 sv = __half22float2(xs2[node * 8 + c]);  // self-loop (prescaled)
        ax = di * (ax + sv.x);
        ay = di * (ay + sv.y);
    }
    // epilogue: 8 nodes of this wave; feature k of node q lives in lane q*8+(k>>1)
    int nb0 = blockIdx.x * 32 + wv * 8;
    for (int q = 0; q < 8; ++q) {
        int nq = nb0 + q;
        if (nq >= N) break;
        float o = bias;
#pragma unroll
        for (int k = 0; k < F_IN; k++) {
            float r = (k & 1) ? bcast_lane(ay, q * 8 + (k >> 1))
                              : bcast_lane(ax, q * 8 + (k >> 1));
            o += r * w1c[k];
        }
        float v = tanhf(o);
        float dq = bcast_lane(di, q * 8);
        h1s[(size_t)nq * HID + lane] = __float2half(dq * v);
    }
}

// ---------- fused layer-2: scalar edge walk + full-wave gather + register mm2 ----------
#define NPB 16   // nodes per block (4 per wave)
__global__ __launch_bounds__(256, 2) void agg_h_mm2(
        const __half* __restrict__ h1s, const float* __restrict__ dinv,
        const int* __restrict__ boff, const int* __restrict__ sedgeS,
        const float* __restrict__ W2, const float* __restrict__ b2,
        __half* __restrict__ h2, int N) {
    int tid = threadIdx.x, wv = tid >> 6, lane = tid & 63;
    float wcol[HID];   // W2 column `lane` in VGPRs, loaded once (coalesced)
#pragma unroll
    for (int k = 0; k < HID; k++) wcol[k] = W2[k * HID + lane];
    float bias = b2[lane];
    int node0 = blockIdx.x * NPB + wv * 4;
    for (int q = 0; q < 4; ++q) {
        int node = node0 + q;
        if (node >= N) break;
        int nu = __builtin_amdgcn_readfirstlane(node);
        int bu = nu >> 6, dl = nu & 63;
        int p0 = boff[bu * 65 + dl], p1 = boff[bu * 65 + dl + 1];
        const int* ep = sedgeS + (size_t)bu * SCAP;
        float acc = 0.f;
        int i = p0;
        for (; i + 8 <= p1; i += 8) {
            int j0 = ep[i + 0], j1 = ep[i + 1], j2 = ep[i + 2], j3 = ep[i + 3];
            int j4 = ep[i + 4], j5 = ep[i + 5], j6 = ep[i + 6], j7 = ep[i + 7];
            float v0 = __half2float(h1s[(size_t)j0 * HID + lane]);
            float v1 = __half2float(h1s[(size_t)j1 * HID + lane]);
            float v2 = __half2float(h1s[(size_t)j2 * HID + lane]);
            float v3 = __half2float(h1s[(size_t)j3 * HID + lane]);
            float v4 = __half2float(h1s[(size_t)j4 * HID + lane]);
            float v5 = __half2float(h1s[(size_t)j5 * HID + lane]);
            float v6 = __half2float(h1s[(size_t)j6 * HID + lane]);
            float v7 = __half2float(h1s[(size_t)j7 * HID + lane]);
            acc += ((v0 + v1) + (v2 + v3)) + ((v4 + v5) + (v6 + v7));
        }
        for (; i < p1; ++i) {
            int j = ep[i];
            acc += __half2float(h1s[(size_t)j * HID + lane]);
        }
        float di = dinv[nu];
        acc += __half2float(h1s[(size_t)nu * HID + lane]);  // self-loop (prescaled)
        float r = di * acc;                                  // lane f holds agg[f]
        float o = bias;
#pragma unroll
        for (int k = 0; k < HID; ++k) o += bcast_lane(r, k) * wcol[k];
        h2[(size_t)nu * HID + lane] = __float2half(tanhf(o));
    }
}

// ---------- pooled[g] = sum over nodes in graph g of [x, h1, h2] ----------
__device__ __forceinline__ int lower_bound_i(const int* b, int n, int v) {
    int lo = 0, hi = n;
    while (lo < hi) { int m = (lo + hi) >> 1; if (b[m] < v) lo = m + 1; else hi = m; }
    return lo;
}

__global__ void pool_kernel(const float* __restrict__ x, const __half* __restrict__ h1s,
                            const float* __restrict__ dinv, const __half* __restrict__ h2,
                            const int* __restrict__ batch, float* __restrict__ pooled, int N) {
    int g = blockIdx.x >> 3;
    int sub = blockIdx.x & 7;
    int start = lower_bound_i(batch, N, g);
    int end = lower_bound_i(batch, N, g + 1);
    int len = end - start;
    int per = (len + 7) >> 3;
    int s = start + sub * per;
    int e = min(s + per, end);
    int f = threadIdx.x;
    if (f >= FC_DIM || s >= e) return;
    float acc = 0.f;
    if (f < F_IN) {
        for (int node = s; node < e; ++node) acc += x[node * F_IN + f];
    } else if (f < F_IN + HID) {
        int off = f - F_IN;
        for (int node = s; node < e; ++node)
            acc += __half2float(h1s[(size_t)node * HID + off]) * (1.0f / dinv[node]);
    } else {
        int off = f - F_IN - HID;
        for (int node = s; node < e; ++node) acc += __half2float(h2[(size_t)node * HID + off]);
    }
    atomicAdd(&pooled[g * FC_DIM + f], acc);
}

// ---------- out = pooled @ fc_W^T + fc_b ----------
__global__ void fc_kernel(const float* __restrict__ pooled, const float* __restrict__ fcW,
                          const float* __restrict__ fcb, float* __restrict__ out) {
    __shared__ float p[FC_DIM];
    int g = blockIdx.x, tid = threadIdx.x;
    if (tid < FC_DIM) p[tid] = pooled[g * FC_DIM + tid];
    __syncthreads();
    if (tid < FC_DIM) {
        float acc = fcb[tid];
        for (int k = 0; k < FC_DIM; k++) acc += p[k] * fcW[tid * FC_DIM + k];
        out[g * FC_DIM + tid] = acc;
    }
}

extern "C" void kernel_launch(void* const* d_in, const int* in_sizes, int n_in,
                              void* d_out, int out_size, void* d_ws, size_t ws_size,
                              hipStream_t stream) {
    const float* x   = (const float*)d_in[0];
    const float* W1  = (const float*)d_in[1];
    const float* b1  = (const float*)d_in[2];
    const float* W2  = (const float*)d_in[3];
    const float* b2  = (const float*)d_in[4];
    const float* fcW = (const float*)d_in[5];
    const float* fcb = (const float*)d_in[6];
    const int*   ei  = (const int*)d_in[7];
    const int*   batch = (const int*)d_in[8];
    const int N = in_sizes[8];
    const int E = in_sizes[7] / 2;
    const int* src = ei;
    const int* dst = ei + E;
    const int NB = (N + 63) / 64;

    char* ws = (char*)d_ws;
    size_t off = 0;
    auto alloc = [&](size_t bytes) -> void* {
        void* p = ws + off; off += (bytes + 255) & ~(size_t)255; return p;
    };
    int*    bcnt2  = (int*)alloc((size_t)NB * NPART * 16 * 4);   // padded cursors
    int*    sedge2 = (int*)alloc((size_t)NB * NPART * PCAP * 4); // partitioned bins
    int*    sedgeS = (int*)alloc((size_t)NB * SCAP * 4);         // sorted buckets
    int*    boff   = (int*)alloc((size_t)NB * 65 * 4);
    float*  dinv   = (float*)alloc((size_t)N * 4);
    __half* xs     = (__half*)alloc((size_t)N * XS_STRIDE * 2);
    __half* h1s    = (__half*)alloc((size_t)N * HID * 2);
    __half* h2     = (__half*)alloc((size_t)N * HID * 2);
    float*  pooled = (float*)alloc((size_t)N_GRAPHS * FC_DIM * 4);
    float* out = (float*)d_out;

    hipMemsetAsync(bcnt2, 0, (size_t)NB * NPART * 16 * 4, stream);
    hipMemsetAsync(pooled, 0, (size_t)N_GRAPHS * FC_DIM * 4, stream);

    count_bin<<<(E / 4 + 255) / 256, 256, 0, stream>>>(src, dst, E, bcnt2, sedge2);
    bucket_sort<<<NB, 256, 0, stream>>>(bcnt2, sedge2, sedgeS, boff, dinv, N);
    make_xs<<<((size_t)N * 16 + 255) / 256, 256, 0, stream>>>(dinv, x, xs, N);
    agg_x_mm1<<<(N + 31) / 32, 256, 0, stream>>>((const __half2*)xs, dinv, boff, sedgeS,
                                                 W1, b1, h1s, N);
    agg_h_mm2<<<(N + NPB - 1) / NPB, 256, 0, stream>>>(h1s, dinv, boff, sedgeS,
                                                       W2, b2, h2, N);
    pool_kernel<<<N_GRAPHS * 8, 192, 0, stream>>>(x, h1s, dinv, h2, batch, pooled, N);
    fc_kernel<<<N_GRAPHS, 192, 0, stream>>>(pooled, fcW, fcb, out);
}

// Round 10
// 299.496 us; speedup vs baseline: 1.0490x; 1.0009x over previous
//
#include <hip/hip_runtime.h>
#include <hip/hip_fp16.h>
#include <math.h>

#define N_GRAPHS 256
#define F_IN 12
#define XS_STRIDE 16
#define HID 64
#define FC_DIM 140
#define NPART 8     // edge-binning partitions (blockIdx & 7; XCD-affine if round-robin)
#define PCAP 224    // per-(bucket,partition) capacity: mean 128, sd ~11 -> +8.5 sigma
#define SCAP 2048   // sorted+padded bucket stride (mean ~1517, +10 sigma headroom)
#define EPT 7       // ceil(NPART*PCAP/256) for the load phase

__device__ __forceinline__ float bcast_lane(float v, int k) {
    return __uint_as_float(__builtin_amdgcn_readlane(__float_as_uint(v), k));
}

// ---------- bucket binning: 4 edges/thread, independent atomic chains ----------
__global__ void count_bin(const int* __restrict__ src, const int* __restrict__ dst, int E,
                          int* __restrict__ bcnt2, int* __restrict__ sedge2) {
    int t = blockIdx.x * blockDim.x + threadIdx.x;
    int e0 = t * 4;
    if (e0 >= E) return;
    int p = blockIdx.x & (NPART - 1);
    if (e0 + 4 <= E) {
        int4 d4 = *(const int4*)&dst[e0];
        int4 s4 = *(const int4*)&src[e0];
        int ds[4] = {d4.x, d4.y, d4.z, d4.w};
        int ss[4] = {s4.x, s4.y, s4.z, s4.w};
#pragma unroll
        for (int k = 0; k < 4; k++) {
            int d = ds[k], b = d >> 6;
            int pos = atomicAdd(&bcnt2[(b * NPART + p) * 16], 1);
            if (pos < PCAP) sedge2[((size_t)b * NPART + p) * PCAP + pos] = ss[k] | ((d & 63) << 20);
        }
    } else {
        for (int e = e0; e < E; ++e) {
            int d = dst[e], b = d >> 6;
            int pos = atomicAdd(&bcnt2[(b * NPART + p) * 16], 1);
            if (pos < PCAP) sedge2[((size_t)b * NPART + p) * PCAP + pos] = src[e] | ((d & 63) << 20);
        }
    }
}

// ---------- per-bucket counting sort + pad-to-16 (sentinel N) + dinv/rdeg + xs ----------
__global__ __launch_bounds__(256) void bucket_sort(
        const int* __restrict__ bcnt2, const int* __restrict__ sedge2,
        const float* __restrict__ x,
        int* __restrict__ sedgeS, int* __restrict__ boff,
        float* __restrict__ dinv, float* __restrict__ rdeg,
        __half* __restrict__ xs, int N) {
    __shared__ int cnt[64];
    __shared__ int cur[64];
    __shared__ int startl[64];
    __shared__ int pcl[64];
    __shared__ float dinvl[64];
    __shared__ int esl[SCAP];
    __shared__ int pbase[NPART + 1];
    int tid = threadIdx.x, b = blockIdx.x;
    if (tid < 64) cnt[tid] = 0;
    if (tid == 0) {
        int s = 0;
        for (int p = 0; p < NPART; p++) {
            pbase[p] = s;
            s += min(bcnt2[(b * NPART + p) * 16], PCAP);
        }
        pbase[NPART] = s;
    }
    __syncthreads();
    int ne = pbase[NPART];
    int ed[EPT], dl[EPT];
#pragma unroll
    for (int k = 0; k < EPT; k++) {
        int idx = tid + k * 256;
        int v = -1;
        if (idx < ne) {
            int p = 0;
#pragma unroll
            for (int q = 1; q < NPART; q++) p += (idx >= pbase[q]);
            v = sedge2[((size_t)b * NPART + p) * PCAP + (idx - pbase[p])];
        }
        ed[k] = v;
        dl[k] = (v >> 20) & 63;
        if (v >= 0) atomicAdd(&cnt[dl[k]], 1);
    }
    __syncthreads();
    if (tid < 64) {
        int c = cnt[tid];
        int pc = (c + 15) & ~15;          // pad each node's segment to mult of 16
        int incl = pc;
#pragma unroll
        for (int off = 1; off < 64; off <<= 1) {
            int t = __shfl_up(incl, off, 64);
            if (tid >= off) incl += t;
        }
        int st = incl - pc;
        startl[tid] = st; cur[tid] = st; pcl[tid] = pc;
        boff[b * 65 + tid] = st;
        if (tid == 63) boff[b * 65 + 64] = incl;
        float di = rsqrtf((float)(c + 1));  // +1 self-loop (real degree)
        dinvl[tid] = di;
        int node = b * 64 + tid;
        if (node < N) { dinv[node] = di; rdeg[node] = sqrtf((float)(c + 1)); }
    }
    __syncthreads();
#pragma unroll
    for (int k = 0; k < EPT; k++) {
        if (ed[k] >= 0) {
            int pos = atomicAdd(&cur[dl[k]], 1);
            esl[pos] = ed[k] & 0xFFFFF;   // src only; dlow implicit in position
        }
    }
    __syncthreads();
    if (tid < 64) {                        // sentinel padding -> zero row N
        int end = startl[tid] + pcl[tid];
        for (int pos = cur[tid]; pos < end; ++pos) esl[pos] = N;
    }
    __syncthreads();
    int netot = startl[63] + pcl[63];
    for (int idx = tid; idx < netot; idx += 256) sedgeS[(size_t)b * SCAP + idx] = esl[idx];
    // fused make_xs for this bucket's nodes
    for (int idx = tid; idx < 64 * XS_STRIDE; idx += 256) {
        int nl = idx >> 4, f = idx & 15;
        int node = b * 64 + nl;
        if (node < N) {
            float v = (f < F_IN) ? dinvl[nl] * x[node * F_IN + f] : 0.f;
            xs[(size_t)node * XS_STRIDE + f] = __float2half(v);
        }
    }
}

// ---------- fused layer-1: 8-lane half2 gather (8 nodes/wave) + mm1 + tanh -> h1s ----------
__global__ __launch_bounds__(256) void agg_x_mm1(
        const __half2* __restrict__ xs2, const float* __restrict__ dinv,
        const int* __restrict__ boff, const int* __restrict__ sedgeS,
        const float* __restrict__ W1, const float* __restrict__ b1,
        __half* __restrict__ h1s, int N) {
    int tid = threadIdx.x, wv = tid >> 6, lane = tid & 63;
    int c = lane & 7, gb = lane & 56;  // group base within wave
    float w1c[F_IN];
#pragma unroll
    for (int k = 0; k < F_IN; k++) w1c[k] = W1[k * HID + lane];  // coalesced
    float bias = b1[lane];
    int node = blockIdx.x * 32 + (tid >> 3);
    float ax = 0.f, ay = 0.f, di = 0.f;
    if (node < N) {
        int b = node >> 6, dlow = node & 63;
        di = dinv[node];
        int p0 = boff[b * 65 + dlow], p1 = boff[b * 65 + dlow + 1];
        const int* ep = sedgeS + (size_t)b * SCAP;
        for (int base = p0; base < p1; base += 8) {   // padded: always full groups
            int el = ep[base + c];
            int j0 = __shfl(el, gb + 0, 64);
            int j1 = __shfl(el, gb + 1, 64);
            int j2 = __shfl(el, gb + 2, 64);
            int j3 = __shfl(el, gb + 3, 64);
            int j4 = __shfl(el, gb + 4, 64);
            int j5 = __shfl(el, gb + 5, 64);
            int j6 = __shfl(el, gb + 6, 64);
            int j7 = __shfl(el, gb + 7, 64);
            float2 v0 = __half22float2(xs2[(size_t)j0 * 8 + c]);
            float2 v1 = __half22float2(xs2[(size_t)j1 * 8 + c]);
            float2 v2 = __half22float2(xs2[(size_t)j2 * 8 + c]);
            float2 v3 = __half22float2(xs2[(size_t)j3 * 8 + c]);
            float2 v4 = __half22float2(xs2[(size_t)j4 * 8 + c]);
            float2 v5 = __half22float2(xs2[(size_t)j5 * 8 + c]);
            float2 v6 = __half22float2(xs2[(size_t)j6 * 8 + c]);
            float2 v7 = __half22float2(xs2[(size_t)j7 * 8 + c]);
            ax += ((v0.x + v1.x) + (v2.x + v3.x)) + ((v4.x + v5.x) + (v6.x + v7.x));
            ay += ((v0.y + v1.y) + (v2.y + v3.y)) + ((v4.y + v5.y) + (v6.y + v7.y));
        }
        float2 sv = __half22float2(xs2[(size_t)node * 8 + c]);  // self-loop (prescaled)
        ax = di * (ax + sv.x);
        ay = di * (ay + sv.y);
    }
    // epilogue: 8 nodes of this wave; feature k of node q lives in lane q*8+(k>>1)
    int nb0 = blockIdx.x * 32 + wv * 8;
    for (int q = 0; q < 8; ++q) {
        int nq = nb0 + q;
        if (nq >= N) break;
        float o = bias;
#pragma unroll
        for (int k = 0; k < F_IN; k++) {
            float r = (k & 1) ? bcast_lane(ay, q * 8 + (k >> 1))
                              : bcast_lane(ax, q * 8 + (k >> 1));
            o += r * w1c[k];
        }
        float v = tanhf(o);
        float dq = bcast_lane(di, q * 8);
        h1s[(size_t)nq * HID + lane] = __float2half(dq * v);
    }
}

// ---------- fused layer-2: scalar edge walk, 16-deep gather + half2-register mm2 ----------
#define NPB 32   // nodes per block (8 per wave)
__global__ __launch_bounds__(256) void agg_h_mm2(
        const __half* __restrict__ h1s, const float* __restrict__ dinv,
        const int* __restrict__ boff, const int* __restrict__ sedgeS,
        const float* __restrict__ W2, const float* __restrict__ b2,
        __half* __restrict__ h2, int N) {
    int tid = threadIdx.x, wv = tid >> 6, lane = tid & 63;
    __half2 wpk[32];   // W2 column `lane`, packed pairs, in 32 VGPRs
#pragma unroll
    for (int k2 = 0; k2 < 32; k2++) {
        float a = W2[(2 * k2) * HID + lane];
        float c = W2[(2 * k2 + 1) * HID + lane];
        wpk[k2] = __floats2half2_rn(a, c);
    }
    float bias = b2[lane];
    int node0 = blockIdx.x * NPB + wv * 8;
    for (int q = 0; q < 8; ++q) {
        int node = node0 + q;
        if (node >= N) break;
        int nu = __builtin_amdgcn_readfirstlane(node);
        int bu = nu >> 6, dl = nu & 63;
        int p0 = boff[bu * 65 + dl], p1 = boff[bu * 65 + dl + 1];
        const int* ep = sedgeS + (size_t)bu * SCAP;
        float acc = 0.f;
        for (int i = p0; i < p1; i += 16) {     // padded: exact multiples of 16
            int jj[16];
#pragma unroll
            for (int k = 0; k < 16; k++) jj[k] = ep[i + k];   // uniform -> s_load
            float vs[16];
#pragma unroll
            for (int k = 0; k < 16; k++)
                vs[k] = __half2float(h1s[(size_t)jj[k] * HID + lane]);
            float s0 = ((vs[0] + vs[1]) + (vs[2] + vs[3])) + ((vs[4] + vs[5]) + (vs[6] + vs[7]));
            float s1 = ((vs[8] + vs[9]) + (vs[10] + vs[11])) + ((vs[12] + vs[13]) + (vs[14] + vs[15]));
            acc += s0 + s1;
        }
        float di = dinv[nu];
        acc += __half2float(h1s[(size_t)nu * HID + lane]);  // self-loop (prescaled)
        float r = di * acc;                                  // lane f holds agg[f]
        float o = bias;
#pragma unroll
        for (int k2 = 0; k2 < 32; ++k2) {
            float2 wf = __half22float2(wpk[k2]);
            o += bcast_lane(r, 2 * k2 + 0) * wf.x;
            o += bcast_lane(r, 2 * k2 + 1) * wf.y;
        }
        h2[(size_t)nu * HID + lane] = __float2half(tanhf(o));
    }
}

// ---------- pooled[g] = sum over nodes in graph g of [x, h1, h2] ----------
__device__ __forceinline__ int lower_bound_i(const int* b, int n, int v) {
    int lo = 0, hi = n;
    while (lo < hi) { int m = (lo + hi) >> 1; if (b[m] < v) lo = m + 1; else hi = m; }
    return lo;
}

__global__ void pool_kernel(const float* __restrict__ x, const __half* __restrict__ h1s,
                            const float* __restrict__ rdeg, const __half* __restrict__ h2,
                            const int* __restrict__ batch, float* __restrict__ pooled, int N) {
    int g = blockIdx.x >> 3;
    int sub = blockIdx.x & 7;
    int start = lower_bound_i(batch, N, g);
    int end = lower_bound_i(batch, N, g + 1);
    int len = end - start;
    int per = (len + 7) >> 3;
    int s = start + sub * per;
    int e = min(s + per, end);
    int f = threadIdx.x;
    if (f >= FC_DIM || s >= e) return;
    float acc = 0.f;
    if (f < F_IN) {
        for (int node = s; node < e; ++node) acc += x[node * F_IN + f];
    } else if (f < F_IN + HID) {
        int off = f - F_IN;
        for (int node = s; node < e; ++node)
            acc += __half2float(h1s[(size_t)node * HID + off]) * rdeg[node];
    } else {
        int off = f - F_IN - HID;
        for (int node = s; node < e; ++node) acc += __half2float(h2[(size_t)node * HID + off]);
    }
    atomicAdd(&pooled[g * FC_DIM + f], acc);
}

// ---------- out = pooled @ fc_W^T + fc_b ----------
__global__ void fc_kernel(const float* __restrict__ pooled, const float* __restrict__ fcW,
                          const float* __restrict__ fcb, float* __restrict__ out) {
    __shared__ float p[FC_DIM];
    int g = blockIdx.x, tid = threadIdx.x;
    if (tid < FC_DIM) p[tid] = pooled[g * FC_DIM + tid];
    __syncthreads();
    if (tid < FC_DIM) {
        float acc = fcb[tid];
        for (int k = 0; k < FC_DIM; k++) acc += p[k] * fcW[tid * FC_DIM + k];
        out[g * FC_DIM + tid] = acc;
    }
}

extern "C" void kernel_launch(void* const* d_in, const int* in_sizes, int n_in,
                              void* d_out, int out_size, void* d_ws, size_t ws_size,
                              hipStream_t stream) {
    const float* x   = (const float*)d_in[0];
    const float* W1  = (const float*)d_in[1];
    const float* b1  = (const float*)d_in[2];
    const float* W2  = (const float*)d_in[3];
    const float* b2  = (const float*)d_in[4];
    const float* fcW = (const float*)d_in[5];
    const float* fcb = (const float*)d_in[6];
    const int*   ei  = (const int*)d_in[7];
    const int*   batch = (const int*)d_in[8];
    const int N = in_sizes[8];
    const int E = in_sizes[7] / 2;
    const int* src = ei;
    const int* dst = ei + E;
    const int NB = (N + 63) / 64;

    char* ws = (char*)d_ws;
    size_t off = 0;
    auto alloc = [&](size_t bytes) -> void* {
        void* p = ws + off; off += (bytes + 255) & ~(size_t)255; return p;
    };
    int*    bcnt2  = (int*)alloc((size_t)NB * NPART * 16 * 4);   // padded cursors
    int*    sedge2 = (int*)alloc((size_t)NB * NPART * PCAP * 4); // partitioned bins
    int*    sedgeS = (int*)alloc((size_t)NB * SCAP * 4);         // sorted+padded buckets
    int*    boff   = (int*)alloc((size_t)NB * 65 * 4);
    float*  dinv   = (float*)alloc((size_t)N * 4);
    float*  rdeg   = (float*)alloc((size_t)N * 4);
    __half* xs     = (__half*)alloc(((size_t)N + 1) * XS_STRIDE * 2);  // +1 zero row
    __half* h1s    = (__half*)alloc(((size_t)N + 1) * HID * 2);        // +1 zero row
    __half* h2     = (__half*)alloc((size_t)N * HID * 2);
    float*  pooled = (float*)alloc((size_t)N_GRAPHS * FC_DIM * 4);
    float* out = (float*)d_out;

    hipMemsetAsync(bcnt2, 0, (size_t)NB * NPART * 16 * 4, stream);
    hipMemsetAsync(pooled, 0, (size_t)N_GRAPHS * FC_DIM * 4, stream);
    hipMemsetAsync(xs + (size_t)N * XS_STRIDE, 0, XS_STRIDE * 2, stream);   // sentinel row
    hipMemsetAsync(h1s + (size_t)N * HID, 0, HID * 2, stream);              // sentinel row

    count_bin<<<(E / 4 + 255) / 256, 256, 0, stream>>>(src, dst, E, bcnt2, sedge2);
    bucket_sort<<<NB, 256, 0, stream>>>(bcnt2, sedge2, x, sedgeS, boff, dinv, rdeg, xs, N);
    agg_x_mm1<<<(N + 31) / 32, 256, 0, stream>>>((const __half2*)xs, dinv, boff, sedgeS,
                                                 W1, b1, h1s, N);
    agg_h_mm2<<<(N + NPB - 1) / NPB, 256, 0, stream>>>(h1s, dinv, boff, sedgeS,
                                                       W2, b2, h2, N);
    pool_kernel<<<N_GRAPHS * 8, 192, 0, stream>>>(x, h1s, rdeg, h2, batch, pooled, N);
    fc_kernel<<<N_GRAPHS, 192, 0, stream>>>(pooled, fcW, fcb, out);
}

// Round 11
// 273.299 us; speedup vs baseline: 1.1495x; 1.0959x over previous
//
#include <hip/hip_runtime.h>
#include <hip/hip_fp16.h>
#include <math.h>

#define N_GRAPHS 256
#define F_IN 12
#define XS_STRIDE 16
#define HID 64
#define FC_DIM 140
#define NPART 8     // edge-binning partitions (blockIdx & 7; XCD-affine if round-robin)
#define PCAP 224    // per-(bucket,partition) capacity: mean 128, sd ~11 -> +8.5 sigma
#define SCAP 2304   // sorted+pad8 bucket stride (mean ~1280; worst-case 1792+448 fits)
#define EPT 7       // ceil(NPART*PCAP/256) for the load phase

__device__ __forceinline__ float bcast_lane(float v, int k) {
    return __uint_as_float(__builtin_amdgcn_readlane(__float_as_uint(v), k));
}

// ---------- bucket binning: 4 edges/thread, independent atomic chains ----------
__global__ void count_bin(const int* __restrict__ src, const int* __restrict__ dst, int E,
                          int* __restrict__ bcnt2, int* __restrict__ sedge2) {
    int t = blockIdx.x * blockDim.x + threadIdx.x;
    int e0 = t * 4;
    if (e0 >= E) return;
    int p = blockIdx.x & (NPART - 1);
    if (e0 + 4 <= E) {
        int4 d4 = *(const int4*)&dst[e0];
        int4 s4 = *(const int4*)&src[e0];
        int ds[4] = {d4.x, d4.y, d4.z, d4.w};
        int ss[4] = {s4.x, s4.y, s4.z, s4.w};
#pragma unroll
        for (int k = 0; k < 4; k++) {
            int d = ds[k], b = d >> 6;
            int pos = atomicAdd(&bcnt2[(b * NPART + p) * 16], 1);
            if (pos < PCAP) sedge2[((size_t)b * NPART + p) * PCAP + pos] = ss[k] | ((d & 63) << 20);
        }
    } else {
        for (int e = e0; e < E; ++e) {
            int d = dst[e], b = d >> 6;
            int pos = atomicAdd(&bcnt2[(b * NPART + p) * 16], 1);
            if (pos < PCAP) sedge2[((size_t)b * NPART + p) * PCAP + pos] = src[e] | ((d & 63) << 20);
        }
    }
}

// ---------- per-bucket counting sort + pad-to-8 (sentinel N) + dinv/rdeg + xs ----------
__global__ __launch_bounds__(256) void bucket_sort(
        const int* __restrict__ bcnt2, const int* __restrict__ sedge2,
        const float* __restrict__ x,
        int* __restrict__ sedgeS, int* __restrict__ boff,
        float* __restrict__ dinv, float* __restrict__ rdeg,
        __half* __restrict__ xs, int N) {
    __shared__ int cnt[64];
    __shared__ int cur[64];
    __shared__ int startl[64];
    __shared__ int pcl[64];
    __shared__ float dinvl[64];
    __shared__ int esl[SCAP];
    __shared__ int pbase[NPART + 1];
    int tid = threadIdx.x, b = blockIdx.x;
    if (tid < 64) cnt[tid] = 0;
    if (tid == 0) {
        int s = 0;
        for (int p = 0; p < NPART; p++) {
            pbase[p] = s;
            s += min(bcnt2[(b * NPART + p) * 16], PCAP);
        }
        pbase[NPART] = s;
    }
    __syncthreads();
    int ne = pbase[NPART];
    int ed[EPT], dl[EPT];
#pragma unroll
    for (int k = 0; k < EPT; k++) {
        int idx = tid + k * 256;
        int v = -1;
        if (idx < ne) {
            int p = 0;
#pragma unroll
            for (int q = 1; q < NPART; q++) p += (idx >= pbase[q]);
            v = sedge2[((size_t)b * NPART + p) * PCAP + (idx - pbase[p])];
        }
        ed[k] = v;
        dl[k] = (v >> 20) & 63;
        if (v >= 0) atomicAdd(&cnt[dl[k]], 1);
    }
    __syncthreads();
    if (tid < 64) {
        int c = cnt[tid];
        int pc = (c + 7) & ~7;            // pad each node's segment to mult of 8
        int incl = pc;
#pragma unroll
        for (int off = 1; off < 64; off <<= 1) {
            int t = __shfl_up(incl, off, 64);
            if (tid >= off) incl += t;
        }
        int st = incl - pc;
        startl[tid] = st; cur[tid] = st; pcl[tid] = pc;
        boff[b * 65 + tid] = st;
        if (tid == 63) boff[b * 65 + 64] = incl;
        float di = rsqrtf((float)(c + 1));  // +1 self-loop (real degree)
        dinvl[tid] = di;
        int node = b * 64 + tid;
        if (node < N) { dinv[node] = di; rdeg[node] = sqrtf((float)(c + 1)); }
    }
    __syncthreads();
#pragma unroll
    for (int k = 0; k < EPT; k++) {
        if (ed[k] >= 0) {
            int pos = atomicAdd(&cur[dl[k]], 1);
            esl[pos] = ed[k] & 0xFFFFF;   // src only; dlow implicit in position
        }
    }
    __syncthreads();
    if (tid < 64) {                        // sentinel padding -> zero row N
        int end = startl[tid] + pcl[tid];
        for (int pos = cur[tid]; pos < end; ++pos) esl[pos] = N;
    }
    __syncthreads();
    int netot = startl[63] + pcl[63];
    for (int idx = tid; idx < netot; idx += 256) sedgeS[(size_t)b * SCAP + idx] = esl[idx];
    // fused make_xs for this bucket's nodes
    for (int idx = tid; idx < 64 * XS_STRIDE; idx += 256) {
        int nl = idx >> 4, f = idx & 15;
        int node = b * 64 + nl;
        if (node < N) {
            float v = (f < F_IN) ? dinvl[nl] * x[node * F_IN + f] : 0.f;
            xs[(size_t)node * XS_STRIDE + f] = __float2half(v);
        }
    }
}

// ---------- fused layer-1: 8-lane half2 gather (8 nodes/wave) + mm1 + h1-pool ----------
__global__ __launch_bounds__(256) void agg_x_mm1(
        const __half2* __restrict__ xs2, const float* __restrict__ dinv,
        const int* __restrict__ boff, const int* __restrict__ sedgeS,
        const float* __restrict__ W1, const float* __restrict__ b1,
        const int* __restrict__ batch, float* __restrict__ pooled,
        __half* __restrict__ h1s, int N) {
    int tid = threadIdx.x, wv = tid >> 6, lane = tid & 63;
    int c = lane & 7, gb = lane & 56;  // group base within wave
    float w1c[F_IN];
#pragma unroll
    for (int k = 0; k < F_IN; k++) w1c[k] = W1[k * HID + lane];  // coalesced
    float bias = b1[lane];
    int node = blockIdx.x * 32 + (tid >> 3);
    float ax = 0.f, ay = 0.f, di = 0.f;
    if (node < N) {
        int b = node >> 6, dlow = node & 63;
        di = dinv[node];
        int p0 = boff[b * 65 + dlow], p1 = boff[b * 65 + dlow + 1];
        const int* ep = sedgeS + (size_t)b * SCAP;
        for (int base = p0; base < p1; base += 8) {   // padded: always full groups
            int el = ep[base + c];
            int j0 = __shfl(el, gb + 0, 64);
            int j1 = __shfl(el, gb + 1, 64);
            int j2 = __shfl(el, gb + 2, 64);
            int j3 = __shfl(el, gb + 3, 64);
            int j4 = __shfl(el, gb + 4, 64);
            int j5 = __shfl(el, gb + 5, 64);
            int j6 = __shfl(el, gb + 6, 64);
            int j7 = __shfl(el, gb + 7, 64);
            float2 v0 = __half22float2(xs2[(size_t)j0 * 8 + c]);
            float2 v1 = __half22float2(xs2[(size_t)j1 * 8 + c]);
            float2 v2 = __half22float2(xs2[(size_t)j2 * 8 + c]);
            float2 v3 = __half22float2(xs2[(size_t)j3 * 8 + c]);
            float2 v4 = __half22float2(xs2[(size_t)j4 * 8 + c]);
            float2 v5 = __half22float2(xs2[(size_t)j5 * 8 + c]);
            float2 v6 = __half22float2(xs2[(size_t)j6 * 8 + c]);
            float2 v7 = __half22float2(xs2[(size_t)j7 * 8 + c]);
            ax += ((v0.x + v1.x) + (v2.x + v3.x)) + ((v4.x + v5.x) + (v6.x + v7.x));
            ay += ((v0.y + v1.y) + (v2.y + v3.y)) + ((v4.y + v5.y) + (v6.y + v7.y));
        }
        float2 sv = __half22float2(xs2[(size_t)node * 8 + c]);  // self-loop (prescaled)
        ax = di * (ax + sv.x);
        ay = di * (ay + sv.y);
    }
    // epilogue: 8 nodes of this wave; feature k of node q lives in lane q*8+(k>>1)
    int nb0 = blockIdx.x * 32 + wv * 8;
    int curg = -1; float pacc = 0.f;
    for (int q = 0; q < 8; ++q) {
        int nq = nb0 + q;
        if (nq >= N) break;
        float o = bias;
#pragma unroll
        for (int k = 0; k < F_IN; k++) {
            float r = (k & 1) ? bcast_lane(ay, q * 8 + (k >> 1))
                              : bcast_lane(ax, q * 8 + (k >> 1));
            o += r * w1c[k];
        }
        float v = tanhf(o);
        float dq = bcast_lane(di, q * 8);
        h1s[(size_t)nq * HID + lane] = __float2half(dq * v);
        int g = batch[nq];
        if (g != curg) {
            if (curg >= 0) atomicAdd(&pooled[curg * FC_DIM + F_IN + lane], pacc);
            pacc = 0.f; curg = g;
        }
        pacc += v;
    }
    if (curg >= 0) atomicAdd(&pooled[curg * FC_DIM + F_IN + lane], pacc);
}

// ---------- fused layer-2: 2-node interleaved scalar walk + register mm2 + h2-pool ----------
#define NPB 16   // nodes per block (4 per wave, as 2 interleaved pairs)
__global__ __launch_bounds__(256) void agg_h_mm2(
        const __half* __restrict__ h1s, const float* __restrict__ dinv,
        const int* __restrict__ boff, const int* __restrict__ sedgeS,
        const float* __restrict__ W2, const float* __restrict__ b2,
        const int* __restrict__ batch, float* __restrict__ pooled, int N) {
    int tid = threadIdx.x, wv = tid >> 6, lane = tid & 63;
    __half2 wpk[32];   // W2 column `lane`, packed pairs, in 32 VGPRs
#pragma unroll
    for (int k2 = 0; k2 < 32; k2++) {
        float a = W2[(2 * k2) * HID + lane];
        float c = W2[(2 * k2 + 1) * HID + lane];
        wpk[k2] = __floats2half2_rn(a, c);
    }
    float bias = b2[lane];
    int node0 = blockIdx.x * NPB + wv * 4;
    int curg = -1; float pacc = 0.f;
#pragma unroll
    for (int qp = 0; qp < 2; ++qp) {
        int na = node0 + 2 * qp;
        if (na >= N) break;
        int nua = __builtin_amdgcn_readfirstlane(na);
        int nub = nua + 1;
        bool hasB = nub < N;
        int bu = nua >> 6;                     // pair never straddles a bucket
        const int* ep = sedgeS + (size_t)bu * SCAP;
        int dla = nua & 63;
        int p0a = boff[bu * 65 + dla], p1a = boff[bu * 65 + dla + 1];
        int p0b = 0, p1b = 0;
        if (hasB) { p0b = p1a; p1b = boff[bu * 65 + dla + 2]; }
        float acca = 0.f, accb = 0.f;
        int ia = p0a, ib = p0b;
        while (ia < p1a && ib < p1b) {         // dual chains: 16 gathers in flight
            int a0 = ep[ia+0], a1 = ep[ia+1], a2 = ep[ia+2], a3 = ep[ia+3];
            int a4 = ep[ia+4], a5 = ep[ia+5], a6 = ep[ia+6], a7 = ep[ia+7];
            int c0 = ep[ib+0], c1 = ep[ib+1], c2 = ep[ib+2], c3 = ep[ib+3];
            int c4 = ep[ib+4], c5 = ep[ib+5], c6 = ep[ib+6], c7 = ep[ib+7];
            float u0 = __half2float(h1s[(size_t)a0 * HID + lane]);
            float u1 = __half2float(h1s[(size_t)a1 * HID + lane]);
            float u2 = __half2float(h1s[(size_t)a2 * HID + lane]);
            float u3 = __half2float(h1s[(size_t)a3 * HID + lane]);
            float u4 = __half2float(h1s[(size_t)a4 * HID + lane]);
            float u5 = __half2float(h1s[(size_t)a5 * HID + lane]);
            float u6 = __half2float(h1s[(size_t)a6 * HID + lane]);
            float u7 = __half2float(h1s[(size_t)a7 * HID + lane]);
            float w0 = __half2float(h1s[(size_t)c0 * HID + lane]);
            float w1 = __half2float(h1s[(size_t)c1 * HID + lane]);
            float w2 = __half2float(h1s[(size_t)c2 * HID + lane]);
            float w3 = __half2float(h1s[(size_t)c3 * HID + lane]);
            float w4 = __half2float(h1s[(size_t)c4 * HID + lane]);
            float w5 = __half2float(h1s[(size_t)c5 * HID + lane]);
            float w6 = __half2float(h1s[(size_t)c6 * HID + lane]);
            float w7 = __half2float(h1s[(size_t)c7 * HID + lane]);
            acca += ((u0 + u1) + (u2 + u3)) + ((u4 + u5) + (u6 + u7));
            accb += ((w0 + w1) + (w2 + w3)) + ((w4 + w5) + (w6 + w7));
            ia += 8; ib += 8;
        }
        while (ia < p1a) {
            int a0 = ep[ia+0], a1 = ep[ia+1], a2 = ep[ia+2], a3 = ep[ia+3];
            int a4 = ep[ia+4], a5 = ep[ia+5], a6 = ep[ia+6], a7 = ep[ia+7];
            float u0 = __half2float(h1s[(size_t)a0 * HID + lane]);
            float u1 = __half2float(h1s[(size_t)a1 * HID + lane]);
            float u2 = __half2float(h1s[(size_t)a2 * HID + lane]);
            float u3 = __half2float(h1s[(size_t)a3 * HID + lane]);
            float u4 = __half2float(h1s[(size_t)a4 * HID + lane]);
            float u5 = __half2float(h1s[(size_t)a5 * HID + lane]);
            float u6 = __half2float(h1s[(size_t)a6 * HID + lane]);
            float u7 = __half2float(h1s[(size_t)a7 * HID + lane]);
            acca += ((u0 + u1) + (u2 + u3)) + ((u4 + u5) + (u6 + u7));
            ia += 8;
        }
        while (ib < p1b) {
            int c0 = ep[ib+0], c1 = ep[ib+1], c2 = ep[ib+2], c3 = ep[ib+3];
            int c4 = ep[ib+4], c5 = ep[ib+5], c6 = ep[ib+6], c7 = ep[ib+7];
            float w0 = __half2float(h1s[(size_t)c0 * HID + lane]);
            float w1 = __half2float(h1s[(size_t)c1 * HID + lane]);
            float w2 = __half2float(h1s[(size_t)c2 * HID + lane]);
            float w3 = __half2float(h1s[(size_t)c3 * HID + lane]);
            float w4 = __half2float(h1s[(size_t)c4 * HID + lane]);
            float w5 = __half2float(h1s[(size_t)c5 * HID + lane]);
            float w6 = __half2float(h1s[(size_t)c6 * HID + lane]);
            float w7 = __half2float(h1s[(size_t)c7 * HID + lane]);
            accb += ((w0 + w1) + (w2 + w3)) + ((w4 + w5) + (w6 + w7));
            ib += 8;
        }
#pragma unroll
        for (int s = 0; s < 2; ++s) {
            int nu = (s == 0) ? nua : nub;
            if (s == 1 && !hasB) break;
            float acc = (s == 0) ? acca : accb;
            float di = dinv[nu];
            acc += __half2float(h1s[(size_t)nu * HID + lane]);  // self-loop (prescaled)
            float r = di * acc;                                  // lane f holds agg[f]
            float o = bias;
#pragma unroll
            for (int k2 = 0; k2 < 32; ++k2) {
                float2 wf = __half22float2(wpk[k2]);
                o += bcast_lane(r, 2 * k2 + 0) * wf.x;
                o += bcast_lane(r, 2 * k2 + 1) * wf.y;
            }
            float val = tanhf(o);
            int g = batch[nu];
            if (g != curg) {
                if (curg >= 0) atomicAdd(&pooled[curg * FC_DIM + F_IN + HID + lane], pacc);
                pacc = 0.f; curg = g;
            }
            pacc += val;
        }
    }
    if (curg >= 0) atomicAdd(&pooled[curg * FC_DIM + F_IN + HID + lane], pacc);
}

// ---------- pooled[g][0..11] = sum of x over graph g (coalesced linear read) ----------
__device__ __forceinline__ int lower_bound_i(const int* b, int n, int v) {
    int lo = 0, hi = n;
    while (lo < hi) { int m = (lo + hi) >> 1; if (b[m] < v) lo = m + 1; else hi = m; }
    return lo;
}

__global__ __launch_bounds__(192) void pool_x(const float* __restrict__ x,
                                              const int* __restrict__ batch,
                                              float* __restrict__ pooled, int N) {
    int g = blockIdx.x;
    int start = lower_bound_i(batch, N, g);
    int end = lower_bound_i(batch, N, g + 1);
    int base = start * F_IN;
    int cnt = (end - start) * F_IN;
    float acc = 0.f;
    for (int i = threadIdx.x; i < cnt; i += 192) acc += x[base + i];  // stride 192 = 16*12
    int f = threadIdx.x % F_IN;
    atomicAdd(&pooled[g * FC_DIM + f], acc);
}

// ---------- out = pooled @ fc_W^T + fc_b ----------
__global__ void fc_kernel(const float* __restrict__ pooled, const float* __restrict__ fcW,
                          const float* __restrict__ fcb, float* __restrict__ out) {
    __shared__ float p[FC_DIM];
    int g = blockIdx.x, tid = threadIdx.x;
    if (tid < FC_DIM) p[tid] = pooled[g * FC_DIM + tid];
    __syncthreads();
    if (tid < FC_DIM) {
        float acc = fcb[tid];
        for (int k = 0; k < FC_DIM; k++) acc += p[k] * fcW[tid * FC_DIM + k];
        out[g * FC_DIM + tid] = acc;
    }
}

extern "C" void kernel_launch(void* const* d_in, const int* in_sizes, int n_in,
                              void* d_out, int out_size, void* d_ws, size_t ws_size,
                              hipStream_t stream) {
    const float* x   = (const float*)d_in[0];
    const float* W1  = (const float*)d_in[1];
    const float* b1  = (const float*)d_in[2];
    const float* W2  = (const float*)d_in[3];
    const float* b2  = (const float*)d_in[4];
    const float* fcW = (const float*)d_in[5];
    const float* fcb = (const float*)d_in[6];
    const int*   ei  = (const int*)d_in[7];
    const int*   batch = (const int*)d_in[8];
    const int N = in_sizes[8];
    const int E = in_sizes[7] / 2;
    const int* src = ei;
    const int* dst = ei + E;
    const int NB = (N + 63) / 64;

    char* ws = (char*)d_ws;
    size_t off = 0;
    auto alloc = [&](size_t bytes) -> void* {
        void* p = ws + off; off += (bytes + 255) & ~(size_t)255; return p;
    };
    int*    bcnt2  = (int*)alloc((size_t)NB * NPART * 16 * 4);   // padded cursors
    int*    sedge2 = (int*)alloc((size_t)NB * NPART * PCAP * 4); // partitioned bins
    int*    sedgeS = (int*)alloc((size_t)NB * SCAP * 4);         // sorted+padded buckets
    int*    boff   = (int*)alloc((size_t)NB * 65 * 4);
    float*  dinv   = (float*)alloc((size_t)N * 4);
    float*  rdeg   = (float*)alloc((size_t)N * 4);
    __half* xs     = (__half*)alloc(((size_t)N + 1) * XS_STRIDE * 2);  // +1 zero row
    __half* h1s    = (__half*)alloc(((size_t)N + 1) * HID * 2);        // +1 zero row
    float*  pooled = (float*)alloc((size_t)N_GRAPHS * FC_DIM * 4);
    float* out = (float*)d_out;

    hipMemsetAsync(bcnt2, 0, (size_t)NB * NPART * 16 * 4, stream);
    hipMemsetAsync(pooled, 0, (size_t)N_GRAPHS * FC_DIM * 4, stream);
    hipMemsetAsync(xs + (size_t)N * XS_STRIDE, 0, XS_STRIDE * 2, stream);   // sentinel row
    hipMemsetAsync(h1s + (size_t)N * HID, 0, HID * 2, stream);              // sentinel row

    count_bin<<<(E / 4 + 255) / 256, 256, 0, stream>>>(src, dst, E, bcnt2, sedge2);
    bucket_sort<<<NB, 256, 0, stream>>>(bcnt2, sedge2, x, sedgeS, boff, dinv, rdeg, xs, N);
    agg_x_mm1<<<(N + 31) / 32, 256, 0, stream>>>((const __half2*)xs, dinv, boff, sedgeS,
                                                 W1, b1, batch, pooled, h1s, N);
    agg_h_mm2<<<(N + NPB - 1) / NPB, 256, 0, stream>>>(h1s, dinv, boff, sedgeS,
                                                       W2, b2, batch, pooled, N);
    pool_x<<<N_GRAPHS, 192, 0, stream>>>(x, batch, pooled, N);
    fc_kernel<<<N_GRAPHS, 192, 0, stream>>>(pooled, fcW, fcb, out);
}

// Round 12
// 269.056 us; speedup vs baseline: 1.1676x; 1.0158x over previous
//
#include <hip/hip_runtime.h>
#include <hip/hip_fp16.h>
#include <math.h>

#define N_GRAPHS 256
#define F_IN 12
#define XS_STRIDE 16
#define HID 64
#define FC_DIM 140
#define NPART 8     // edge-binning partitions (blockIdx & 7; XCD-affine if round-robin)
#define PCAP 224    // per-(bucket,partition) capacity: mean 128, sd ~11 -> +8.5 sigma
#define SCAP 2304   // sorted+pad8 bucket stride (worst-case 1792+448 = 2240 fits)
#define EPT 7       // ceil(NPART*PCAP/256) for the load phase

typedef _Float16 h2v __attribute__((ext_vector_type(2)));

__device__ __forceinline__ float bcast_lane(float v, int k) {
    return __uint_as_float(__builtin_amdgcn_readlane(__float_as_uint(v), k));
}
__device__ __forceinline__ unsigned bcast_lane_u(unsigned v, int k) {
    return __builtin_amdgcn_readlane(v, k);
}

// ---------- bucket binning: 4 edges/thread, independent atomic chains ----------
__global__ void count_bin(const int* __restrict__ src, const int* __restrict__ dst, int E,
                          int* __restrict__ bcnt2, int* __restrict__ sedge2) {
    int t = blockIdx.x * blockDim.x + threadIdx.x;
    int e0 = t * 4;
    if (e0 >= E) return;
    int p = blockIdx.x & (NPART - 1);
    if (e0 + 4 <= E) {
        int4 d4 = *(const int4*)&dst[e0];
        int4 s4 = *(const int4*)&src[e0];
        int ds[4] = {d4.x, d4.y, d4.z, d4.w};
        int ss[4] = {s4.x, s4.y, s4.z, s4.w};
#pragma unroll
        for (int k = 0; k < 4; k++) {
            int d = ds[k], b = d >> 6;
            int pos = atomicAdd(&bcnt2[(b * NPART + p) * 16], 1);
            if (pos < PCAP) sedge2[((size_t)b * NPART + p) * PCAP + pos] = ss[k] | ((d & 63) << 20);
        }
    } else {
        for (int e = e0; e < E; ++e) {
            int d = dst[e], b = d >> 6;
            int pos = atomicAdd(&bcnt2[(b * NPART + p) * 16], 1);
            if (pos < PCAP) sedge2[((size_t)b * NPART + p) * PCAP + pos] = src[e] | ((d & 63) << 20);
        }
    }
}

// ---------- per-bucket counting sort + pad-to-8 (sentinel N) + dinv + xs ----------
__global__ __launch_bounds__(256) void bucket_sort(
        const int* __restrict__ bcnt2, const int* __restrict__ sedge2,
        const float* __restrict__ x,
        int* __restrict__ sedgeS, int* __restrict__ boff,
        float* __restrict__ dinv, __half* __restrict__ xs, int N) {
    __shared__ int cnt[64];
    __shared__ int cur[64];
    __shared__ int startl[64];
    __shared__ int pcl[64];
    __shared__ float dinvl[64];
    __shared__ int esl[SCAP];
    __shared__ int pbase[NPART + 1];
    int tid = threadIdx.x, b = blockIdx.x;
    if (tid < 64) cnt[tid] = 0;
    if (tid == 0) {
        int s = 0;
        for (int p = 0; p < NPART; p++) {
            pbase[p] = s;
            s += min(bcnt2[(b * NPART + p) * 16], PCAP);
        }
        pbase[NPART] = s;
    }
    __syncthreads();
    int ne = pbase[NPART];
    int ed[EPT], dl[EPT];
#pragma unroll
    for (int k = 0; k < EPT; k++) {
        int idx = tid + k * 256;
        int v = -1;
        if (idx < ne) {
            int p = 0;
#pragma unroll
            for (int q = 1; q < NPART; q++) p += (idx >= pbase[q]);
            v = sedge2[((size_t)b * NPART + p) * PCAP + (idx - pbase[p])];
        }
        ed[k] = v;
        dl[k] = (v >> 20) & 63;
        if (v >= 0) atomicAdd(&cnt[dl[k]], 1);
    }
    __syncthreads();
    if (tid < 64) {
        int c = cnt[tid];
        int pc = (c + 7) & ~7;            // pad each node's segment to mult of 8
        int incl = pc;
#pragma unroll
        for (int off = 1; off < 64; off <<= 1) {
            int t = __shfl_up(incl, off, 64);
            if (tid >= off) incl += t;
        }
        int st = incl - pc;
        startl[tid] = st; cur[tid] = st; pcl[tid] = pc;
        boff[b * 65 + tid] = st;
        if (tid == 63) boff[b * 65 + 64] = incl;
        float di = rsqrtf((float)(c + 1));  // +1 self-loop (real degree)
        dinvl[tid] = di;
        int node = b * 64 + tid;
        if (node < N) dinv[node] = di;
    }
    __syncthreads();
#pragma unroll
    for (int k = 0; k < EPT; k++) {
        if (ed[k] >= 0) {
            int pos = atomicAdd(&cur[dl[k]], 1);
            esl[pos] = ed[k] & 0xFFFFF;   // src only; dlow implicit in position
        }
    }
    __syncthreads();
    if (tid < 64) {                        // sentinel padding -> zero row N
        int end = startl[tid] + pcl[tid];
        for (int pos = cur[tid]; pos < end; ++pos) esl[pos] = N;
    }
    __syncthreads();
    int netot = startl[63] + pcl[63];
    for (int idx = tid; idx < netot; idx += 256) sedgeS[(size_t)b * SCAP + idx] = esl[idx];
    // fused make_xs for this bucket's nodes
    for (int idx = tid; idx < 64 * XS_STRIDE; idx += 256) {
        int nl = idx >> 4, f = idx & 15;
        int node = b * 64 + nl;
        if (node < N) {
            float v = (f < F_IN) ? dinvl[nl] * x[node * F_IN + f] : 0.f;
            xs[(size_t)node * XS_STRIDE + f] = __float2half(v);
        }
    }
}

// ---------- fused layer-1: 8-lane half2 gather, 16-deep, + mm1 + h1-pool ----------
__global__ __launch_bounds__(256) void agg_x_mm1(
        const __half2* __restrict__ xs2, const float* __restrict__ dinv,
        const int* __restrict__ boff, const int* __restrict__ sedgeS,
        const float* __restrict__ W1, const float* __restrict__ b1,
        const int* __restrict__ batch, float* __restrict__ pooled,
        __half* __restrict__ h1s, int N) {
    int tid = threadIdx.x, wv = tid >> 6, lane = tid & 63;
    int c = lane & 7, gb = lane & 56;  // group base within wave
    float w1c[F_IN];
#pragma unroll
    for (int k = 0; k < F_IN; k++) w1c[k] = W1[k * HID + lane];  // coalesced
    float bias = b1[lane];
    int node = blockIdx.x * 32 + (tid >> 3);
    float ax = 0.f, ay = 0.f, di = 0.f;
    if (node < N) {
        int b = node >> 6, dlow = node & 63;
        di = dinv[node];
        int p0 = boff[b * 65 + dlow], p1 = boff[b * 65 + dlow + 1];
        const int* ep = sedgeS + (size_t)b * SCAP;
        int base = p0;
        for (; base + 16 <= p1; base += 16) {   // 16 gathers in flight
            int ela = ep[base + c];
            int elb = ep[base + 8 + c];
            int ja[8], jb[8];
#pragma unroll
            for (int k = 0; k < 8; k++) ja[k] = __shfl(ela, gb + k, 64);
#pragma unroll
            for (int k = 0; k < 8; k++) jb[k] = __shfl(elb, gb + k, 64);
            float2 va[8], vb[8];
#pragma unroll
            for (int k = 0; k < 8; k++) va[k] = __half22float2(xs2[(size_t)ja[k] * 8 + c]);
#pragma unroll
            for (int k = 0; k < 8; k++) vb[k] = __half22float2(xs2[(size_t)jb[k] * 8 + c]);
#pragma unroll
            for (int k = 0; k < 8; k++) { ax += va[k].x + vb[k].x; ay += va[k].y + vb[k].y; }
        }
        if (base < p1) {                        // remainder: exactly 8 (pad-8)
            int el = ep[base + c];
            int j[8];
#pragma unroll
            for (int k = 0; k < 8; k++) j[k] = __shfl(el, gb + k, 64);
#pragma unroll
            for (int k = 0; k < 8; k++) {
                float2 v = __half22float2(xs2[(size_t)j[k] * 8 + c]);
                ax += v.x; ay += v.y;
            }
        }
        float2 sv = __half22float2(xs2[(size_t)node * 8 + c]);  // self-loop (prescaled)
        ax = di * (ax + sv.x);
        ay = di * (ay + sv.y);
    }
    // epilogue: 8 nodes of this wave; feature k of node q lives in lane q*8+(k>>1)
    int nb0 = blockIdx.x * 32 + wv * 8;
    int curg = -1; float pacc = 0.f;
    for (int q = 0; q < 8; ++q) {
        int nq = nb0 + q;
        if (nq >= N) break;
        float o = bias;
#pragma unroll
        for (int k = 0; k < F_IN; k++) {
            float r = (k & 1) ? bcast_lane(ay, q * 8 + (k >> 1))
                              : bcast_lane(ax, q * 8 + (k >> 1));
            o += r * w1c[k];
        }
        float v = tanhf(o);
        float dq = bcast_lane(di, q * 8);
        h1s[(size_t)nq * HID + lane] = __float2half(dq * v);
        int g = batch[nq];
        if (g != curg) {
            if (curg >= 0) atomicAdd(&pooled[curg * FC_DIM + F_IN + lane], pacc);
            pacc = 0.f; curg = g;
        }
        pacc += v;
    }
    if (curg >= 0) atomicAdd(&pooled[curg * FC_DIM + F_IN + lane], pacc);
}

// ---------- fused layer-2: 4-chain interleaved walk (32 in flight) + dot2 mm2 + pool ----------
#define NPB 16   // nodes per block (4 per wave, 4 interleaved chains)
__global__ __launch_bounds__(256) void agg_h_mm2(
        const __half* __restrict__ h1s, const float* __restrict__ dinv,
        const int* __restrict__ boff, const int* __restrict__ sedgeS,
        const float* __restrict__ W2, const float* __restrict__ b2,
        const int* __restrict__ batch, float* __restrict__ pooled, int N) {
    int tid = threadIdx.x, wv = tid >> 6, lane = tid & 63;
    h2v wpk[32];   // W2 column `lane`, packed pairs (32 VGPRs)
#pragma unroll
    for (int k2 = 0; k2 < 32; k2++) {
        h2v w; w[0] = (_Float16)W2[(2 * k2) * HID + lane];
        w[1] = (_Float16)W2[(2 * k2 + 1) * HID + lane];
        wpk[k2] = w;
    }
    float bias = b2[lane];
    int node0 = blockIdx.x * NPB + wv * 4;
    if (node0 >= N) return;
    int n0 = __builtin_amdgcn_readfirstlane(node0);
    int bu = n0 >> 6, dl0 = n0 & 63;       // 4 consecutive nodes never straddle a bucket
    const int* ep = sedgeS + (size_t)bu * SCAP;
    int bnd[5];
#pragma unroll
    for (int t = 0; t < 5; t++) bnd[t] = boff[bu * 65 + dl0 + t];
    int ii[4]; float acc[4];
#pragma unroll
    for (int s = 0; s < 4; s++) { ii[s] = bnd[s]; acc[s] = 0.f; }
    for (;;) {
        bool a0 = ii[0] < bnd[1], a1 = ii[1] < bnd[2], a2 = ii[2] < bnd[3], a3 = ii[3] < bnd[4];
        if (!(a0 | a1 | a2 | a3)) break;
        __half hv[4][8];
#pragma unroll
        for (int s = 0; s < 4; s++) {
            bool act = (s == 0) ? a0 : (s == 1) ? a1 : (s == 2) ? a2 : a3;
            if (act) {
                int j[8];
#pragma unroll
                for (int k = 0; k < 8; k++) j[k] = ep[ii[s] + k];   // uniform -> s_load
#pragma unroll
                for (int k = 0; k < 8; k++) hv[s][k] = h1s[(size_t)j[k] * HID + lane];
            }
        }
#pragma unroll
        for (int s = 0; s < 4; s++) {
            bool act = (s == 0) ? a0 : (s == 1) ? a1 : (s == 2) ? a2 : a3;
            if (act) {
                float t0 = __half2float(hv[s][0]) + __half2float(hv[s][1]);
                float t1 = __half2float(hv[s][2]) + __half2float(hv[s][3]);
                float t2 = __half2float(hv[s][4]) + __half2float(hv[s][5]);
                float t3 = __half2float(hv[s][6]) + __half2float(hv[s][7]);
                acc[s] += (t0 + t1) + (t2 + t3);
                ii[s] += 8;
            }
        }
    }
    int curg = -1; float pacc = 0.f;
#pragma unroll
    for (int s = 0; s < 4; ++s) {
        int nu = n0 + s;
        if (nu >= N) break;
        float di = dinv[nu];
        float a = acc[s] + __half2float(h1s[(size_t)nu * HID + lane]);  // self-loop
        float r = di * a;                     // lane f holds agg[f]
        // pack r (fp16) pairs: lane k (k<32) gets {r[2k], r[2k+1]}
        unsigned rhu = (unsigned)__half_as_ushort(__float2half(r));
        unsigned lo = (unsigned)__builtin_amdgcn_ds_bpermute(lane * 8, (int)rhu);
        unsigned hi = (unsigned)__builtin_amdgcn_ds_bpermute(lane * 8 + 4, (int)rhu);
        unsigned pk = (lo & 0xFFFFu) | (hi << 16);
        float o = bias;
#if __has_builtin(__builtin_amdgcn_fdot2)
#pragma unroll
        for (int k2 = 0; k2 < 32; ++k2) {
            unsigned pr = bcast_lane_u(pk, k2);
            o = __builtin_amdgcn_fdot2(__builtin_bit_cast(h2v, pr), wpk[k2], o, false);
        }
#else
#pragma unroll
        for (int k2 = 0; k2 < 32; ++k2) {
            unsigned pr = bcast_lane_u(pk, k2);
            float rx = __half2float(__ushort_as_half((unsigned short)(pr & 0xFFFF)));
            float ry = __half2float(__ushort_as_half((unsigned short)(pr >> 16)));
            o += rx * (float)wpk[k2][0] + ry * (float)wpk[k2][1];
        }
#endif
        float val = tanhf(o);
        int g = batch[nu];
        if (g != curg) {
            if (curg >= 0) atomicAdd(&pooled[curg * FC_DIM + F_IN + HID + lane], pacc);
            pacc = 0.f; curg = g;
        }
        pacc += val;
    }
    if (curg >= 0) atomicAdd(&pooled[curg * FC_DIM + F_IN + HID + lane], pacc);
}

// ---------- fc: fused x-pool (graph-local, coalesced) + matvec ----------
__device__ __forceinline__ int lower_bound_i(const int* b, int n, int v) {
    int lo = 0, hi = n;
    while (lo < hi) { int m = (lo + hi) >> 1; if (b[m] < v) lo = m + 1; else hi = m; }
    return lo;
}

__global__ __launch_bounds__(192) void fc_kernel(
        const float* __restrict__ x, const int* __restrict__ batch,
        const float* __restrict__ pooled, const float* __restrict__ fcW,
        const float* __restrict__ fcb, float* __restrict__ out, int N) {
    __shared__ float p[FC_DIM];
    int g = blockIdx.x, tid = threadIdx.x;
    if (tid < FC_DIM) p[tid] = (tid < F_IN) ? 0.f : pooled[g * FC_DIM + tid];
    __syncthreads();
    int start = lower_bound_i(batch, N, g);
    int end = lower_bound_i(batch, N, g + 1);
    int base = start * F_IN;
    int cnt = (end - start) * F_IN;
    float acc = 0.f;
    for (int i = tid; i < cnt; i += 192) acc += x[base + i];  // stride 192 = 16*12
    atomicAdd(&p[tid % F_IN], acc);
    __syncthreads();
    if (tid < FC_DIM) {
        float o = fcb[tid];
        for (int k = 0; k < FC_DIM; k++) o += p[k] * fcW[tid * FC_DIM + k];
        out[g * FC_DIM + tid] = o;
    }
}

extern "C" void kernel_launch(void* const* d_in, const int* in_sizes, int n_in,
                              void* d_out, int out_size, void* d_ws, size_t ws_size,
                              hipStream_t stream) {
    const float* x   = (const float*)d_in[0];
    const float* W1  = (const float*)d_in[1];
    const float* b1  = (const float*)d_in[2];
    const float* W2  = (const float*)d_in[3];
    const float* b2  = (const float*)d_in[4];
    const float* fcW = (const float*)d_in[5];
    const float* fcb = (const float*)d_in[6];
    const int*   ei  = (const int*)d_in[7];
    const int*   batch = (const int*)d_in[8];
    const int N = in_sizes[8];
    const int E = in_sizes[7] / 2;
    const int* src = ei;
    const int* dst = ei + E;
    const int NB = (N + 63) / 64;

    char* ws = (char*)d_ws;
    size_t off = 0;
    auto alloc = [&](size_t bytes) -> void* {
        void* p = ws + off; off += (bytes + 255) & ~(size_t)255; return p;
    };
    int*    bcnt2  = (int*)alloc((size_t)NB * NPART * 16 * 4);   // padded cursors
    int*    sedge2 = (int*)alloc((size_t)NB * NPART * PCAP * 4); // partitioned bins
    int*    sedgeS = (int*)alloc((size_t)NB * SCAP * 4);         // sorted+padded buckets
    int*    boff   = (int*)alloc((size_t)NB * 65 * 4);
    float*  dinv   = (float*)alloc((size_t)N * 4);
    __half* xs     = (__half*)alloc(((size_t)N + 1) * XS_STRIDE * 2);  // +1 zero row
    __half* h1s    = (__half*)alloc(((size_t)N + 1) * HID * 2);        // +1 zero row
    float*  pooled = (float*)alloc((size_t)N_GRAPHS * FC_DIM * 4);
    float* out = (float*)d_out;

    hipMemsetAsync(bcnt2, 0, (size_t)NB * NPART * 16 * 4, stream);
    hipMemsetAsync(pooled, 0, (size_t)N_GRAPHS * FC_DIM * 4, stream);
    hipMemsetAsync(xs + (size_t)N * XS_STRIDE, 0, XS_STRIDE * 2, stream);   // sentinel row
    hipMemsetAsync(h1s + (size_t)N * HID, 0, HID * 2, stream);              // sentinel row

    count_bin<<<(E / 4 + 255) / 256, 256, 0, stream>>>(src, dst, E, bcnt2, sedge2);
    bucket_sort<<<NB, 256, 0, stream>>>(bcnt2, sedge2, x, sedgeS, boff, dinv, xs, N);
    agg_x_mm1<<<(N + 31) / 32, 256, 0, stream>>>((const __half2*)xs, dinv, boff, sedgeS,
                                                 W1, b1, batch, pooled, h1s, N);
    agg_h_mm2<<<(N + NPB - 1) / NPB, 256, 0, stream>>>(h1s, dinv, boff, sedgeS,
                                                       W2, b2, batch, pooled, N);
    fc_kernel<<<N_GRAPHS, 192, 0, stream>>>(x, batch, pooled, fcW, fcb, out, N);
}

// Round 13
// 268.549 us; speedup vs baseline: 1.1698x; 1.0019x over previous
//
#include <hip/hip_runtime.h>
#include <hip/hip_fp16.h>
#include <math.h>

#define N_GRAPHS 256
#define F_IN 12
#define XS_STRIDE 16
#define HID 64
#define FC_DIM 140
#define NPART 8     // edge-binning partitions = physical XCD (HW_REG_XCC_ID)
#define PCAP 224    // per-(bucket,partition) capacity: mean 128, sd ~11 -> +8.5 sigma
#define SCAP 2304   // sorted+pad8 bucket stride (worst-case 1792+448 = 2240 fits)
#define EPT 7       // ceil(NPART*PCAP/256) for the load phase

typedef _Float16 h2v __attribute__((ext_vector_type(2)));

__device__ __forceinline__ float bcast_lane(float v, int k) {
    return __uint_as_float(__builtin_amdgcn_readlane(__float_as_uint(v), k));
}
__device__ __forceinline__ unsigned bcast_lane_u(unsigned v, int k) {
    return __builtin_amdgcn_readlane(v, k);
}
__device__ __forceinline__ int xcc_id() {
    int x;
    asm volatile("s_getreg_b32 %0, hwreg(HW_REG_XCC_ID, 0, 4)" : "=s"(x));
    return x & (NPART - 1);
}

// ---------- bucket binning: 4 edges/thread; partition = PHYSICAL XCD ----------
// All stores/atomics to region (b,p) issue from XCD p only -> local-L2
// write combining (~1x amplification), no cross-XCD line ping-pong.
__global__ void count_bin(const int* __restrict__ src, const int* __restrict__ dst, int E,
                          int* __restrict__ bcnt2, int* __restrict__ sedge2) {
    int t = blockIdx.x * blockDim.x + threadIdx.x;
    int e0 = t * 4;
    if (e0 >= E) return;
    int p = xcc_id();
    if (e0 + 4 <= E) {
        int4 d4 = *(const int4*)&dst[e0];
        int4 s4 = *(const int4*)&src[e0];
        int ds[4] = {d4.x, d4.y, d4.z, d4.w};
        int ss[4] = {s4.x, s4.y, s4.z, s4.w};
#pragma unroll
        for (int k = 0; k < 4; k++) {
            int d = ds[k], b = d >> 6;
            int pos = atomicAdd(&bcnt2[(b * NPART + p) * 16], 1);
            if (pos < PCAP) sedge2[((size_t)b * NPART + p) * PCAP + pos] = ss[k] | ((d & 63) << 20);
        }
    } else {
        for (int e = e0; e < E; ++e) {
            int d = dst[e], b = d >> 6;
            int pos = atomicAdd(&bcnt2[(b * NPART + p) * 16], 1);
            if (pos < PCAP) sedge2[((size_t)b * NPART + p) * PCAP + pos] = src[e] | ((d & 63) << 20);
        }
    }
}

// ---------- per-bucket counting sort + pad-to-8 (sentinel N) + dinv + xs ----------
__global__ __launch_bounds__(256) void bucket_sort(
        const int* __restrict__ bcnt2, const int* __restrict__ sedge2,
        const float* __restrict__ x,
        int* __restrict__ sedgeS, int* __restrict__ boff,
        float* __restrict__ dinv, __half* __restrict__ xs, int N) {
    __shared__ int cnt[64];
    __shared__ int cur[64];
    __shared__ int startl[64];
    __shared__ int pcl[64];
    __shared__ float dinvl[64];
    __shared__ int esl[SCAP];
    __shared__ int pbase[NPART + 1];
    int tid = threadIdx.x, b = blockIdx.x;
    if (tid < 64) cnt[tid] = 0;
    if (tid == 0) {
        int s = 0;
        for (int p = 0; p < NPART; p++) {
            pbase[p] = s;
            s += min(bcnt2[(b * NPART + p) * 16], PCAP);
        }
        pbase[NPART] = s;
    }
    __syncthreads();
    int ne = pbase[NPART];
    int ed[EPT], dl[EPT];
#pragma unroll
    for (int k = 0; k < EPT; k++) {
        int idx = tid + k * 256;
        int v = -1;
        if (idx < ne) {
            int p = 0;
#pragma unroll
            for (int q = 1; q < NPART; q++) p += (idx >= pbase[q]);
            v = sedge2[((size_t)b * NPART + p) * PCAP + (idx - pbase[p])];
        }
        ed[k] = v;
        dl[k] = (v >> 20) & 63;
        if (v >= 0) atomicAdd(&cnt[dl[k]], 1);
    }
    __syncthreads();
    if (tid < 64) {
        int c = cnt[tid];
        int pc = (c + 7) & ~7;            // pad each node's segment to mult of 8
        int incl = pc;
#pragma unroll
        for (int off = 1; off < 64; off <<= 1) {
            int t = __shfl_up(incl, off, 64);
            if (tid >= off) incl += t;
        }
        int st = incl - pc;
        startl[tid] = st; cur[tid] = st; pcl[tid] = pc;
        boff[b * 65 + tid] = st;
        if (tid == 63) boff[b * 65 + 64] = incl;
        float di = rsqrtf((float)(c + 1));  // +1 self-loop (real degree)
        dinvl[tid] = di;
        int node = b * 64 + tid;
        if (node < N) dinv[node] = di;
    }
    __syncthreads();
#pragma unroll
    for (int k = 0; k < EPT; k++) {
        if (ed[k] >= 0) {
            int pos = atomicAdd(&cur[dl[k]], 1);
            esl[pos] = ed[k] & 0xFFFFF;   // src only; dlow implicit in position
        }
    }
    __syncthreads();
    if (tid < 64) {                        // sentinel padding -> zero row N
        int end = startl[tid] + pcl[tid];
        for (int pos = cur[tid]; pos < end; ++pos) esl[pos] = N;
    }
    __syncthreads();
    int netot = startl[63] + pcl[63];
    for (int idx = tid; idx < netot; idx += 256) sedgeS[(size_t)b * SCAP + idx] = esl[idx];
    // fused make_xs for this bucket's nodes
    for (int idx = tid; idx < 64 * XS_STRIDE; idx += 256) {
        int nl = idx >> 4, f = idx & 15;
        int node = b * 64 + nl;
        if (node < N) {
            float v = (f < F_IN) ? dinvl[nl] * x[node * F_IN + f] : 0.f;
            xs[(size_t)node * XS_STRIDE + f] = __float2half(v);
        }
    }
}

// ---------- fused layer-1: 8-lane half2 gather, 16-deep, + mm1 + h1-pool ----------
__global__ __launch_bounds__(256) void agg_x_mm1(
        const __half2* __restrict__ xs2, const float* __restrict__ dinv,
        const int* __restrict__ boff, const int* __restrict__ sedgeS,
        const float* __restrict__ W1, const float* __restrict__ b1,
        const int* __restrict__ batch, float* __restrict__ pooled,
        __half* __restrict__ h1s, int N) {
    int tid = threadIdx.x, wv = tid >> 6, lane = tid & 63;
    int c = lane & 7, gb = lane & 56;  // group base within wave
    float w1c[F_IN];
#pragma unroll
    for (int k = 0; k < F_IN; k++) w1c[k] = W1[k * HID + lane];  // coalesced
    float bias = b1[lane];
    int node = blockIdx.x * 32 + (tid >> 3);
    float ax = 0.f, ay = 0.f, di = 0.f;
    if (node < N) {
        int b = node >> 6, dlow = node & 63;
        di = dinv[node];
        int p0 = boff[b * 65 + dlow], p1 = boff[b * 65 + dlow + 1];
        const int* ep = sedgeS + (size_t)b * SCAP;
        int base = p0;
        for (; base + 16 <= p1; base += 16) {   // 16 gathers in flight
            int ela = ep[base + c];
            int elb = ep[base + 8 + c];
            int ja[8], jb[8];
#pragma unroll
            for (int k = 0; k < 8; k++) ja[k] = __shfl(ela, gb + k, 64);
#pragma unroll
            for (int k = 0; k < 8; k++) jb[k] = __shfl(elb, gb + k, 64);
            float2 va[8], vb[8];
#pragma unroll
            for (int k = 0; k < 8; k++) va[k] = __half22float2(xs2[(size_t)ja[k] * 8 + c]);
#pragma unroll
            for (int k = 0; k < 8; k++) vb[k] = __half22float2(xs2[(size_t)jb[k] * 8 + c]);
#pragma unroll
            for (int k = 0; k < 8; k++) { ax += va[k].x + vb[k].x; ay += va[k].y + vb[k].y; }
        }
        if (base < p1) {                        // remainder: exactly 8 (pad-8)
            int el = ep[base + c];
            int j[8];
#pragma unroll
            for (int k = 0; k < 8; k++) j[k] = __shfl(el, gb + k, 64);
#pragma unroll
            for (int k = 0; k < 8; k++) {
                float2 v = __half22float2(xs2[(size_t)j[k] * 8 + c]);
                ax += v.x; ay += v.y;
            }
        }
        float2 sv = __half22float2(xs2[(size_t)node * 8 + c]);  // self-loop (prescaled)
        ax = di * (ax + sv.x);
        ay = di * (ay + sv.y);
    }
    // epilogue: 8 nodes of this wave; feature k of node q lives in lane q*8+(k>>1)
    int nb0 = blockIdx.x * 32 + wv * 8;
    int curg = -1; float pacc = 0.f;
    for (int q = 0; q < 8; ++q) {
        int nq = nb0 + q;
        if (nq >= N) break;
        float o = bias;
#pragma unroll
        for (int k = 0; k < F_IN; k++) {
            float r = (k & 1) ? bcast_lane(ay, q * 8 + (k >> 1))
                              : bcast_lane(ax, q * 8 + (k >> 1));
            o += r * w1c[k];
        }
        float v = tanhf(o);
        float dq = bcast_lane(di, q * 8);
        h1s[(size_t)nq * HID + lane] = __float2half(dq * v);
        int g = batch[nq];
        if (g != curg) {
            if (curg >= 0) atomicAdd(&pooled[curg * FC_DIM + F_IN + lane], pacc);
            pacc = 0.f; curg = g;
        }
        pacc += v;
    }
    if (curg >= 0) atomicAdd(&pooled[curg * FC_DIM + F_IN + lane], pacc);
}

// ---------- fused layer-2: 4-chain interleaved walk (32 in flight) + dot2 mm2 + pool ----------
#define NPB 16   // nodes per block (4 per wave, 4 interleaved chains)
__global__ __launch_bounds__(256) void agg_h_mm2(
        const __half* __restrict__ h1s, const float* __restrict__ dinv,
        const int* __restrict__ boff, const int* __restrict__ sedgeS,
        const float* __restrict__ W2, const float* __restrict__ b2,
        const int* __restrict__ batch, float* __restrict__ pooled, int N) {
    int tid = threadIdx.x, wv = tid >> 6, lane = tid & 63;
    h2v wpk[32];   // W2 column `lane`, packed pairs (32 VGPRs)
#pragma unroll
    for (int k2 = 0; k2 < 32; k2++) {
        h2v w; w[0] = (_Float16)W2[(2 * k2) * HID + lane];
        w[1] = (_Float16)W2[(2 * k2 + 1) * HID + lane];
        wpk[k2] = w;
    }
    float bias = b2[lane];
    int node0 = blockIdx.x * NPB + wv * 4;
    if (node0 >= N) return;
    int n0 = __builtin_amdgcn_readfirstlane(node0);
    int bu = n0 >> 6, dl0 = n0 & 63;       // 4 consecutive nodes never straddle a bucket
    const int* ep = sedgeS + (size_t)bu * SCAP;
    int bnd[5];
#pragma unroll
    for (int t = 0; t < 5; t++) bnd[t] = boff[bu * 65 + dl0 + t];
    int ii[4]; float acc[4];
#pragma unroll
    for (int s = 0; s < 4; s++) { ii[s] = bnd[s]; acc[s] = 0.f; }
    for (;;) {
        bool a0 = ii[0] < bnd[1], a1 = ii[1] < bnd[2], a2 = ii[2] < bnd[3], a3 = ii[3] < bnd[4];
        if (!(a0 | a1 | a2 | a3)) break;
        __half hv[4][8];
#pragma unroll
        for (int s = 0; s < 4; s++) {
            bool act = (s == 0) ? a0 : (s == 1) ? a1 : (s == 2) ? a2 : a3;
            if (act) {
                int j[8];
#pragma unroll
                for (int k = 0; k < 8; k++) j[k] = ep[ii[s] + k];   // uniform -> s_load
#pragma unroll
                for (int k = 0; k < 8; k++) hv[s][k] = h1s[(size_t)j[k] * HID + lane];
            }
        }
#pragma unroll
        for (int s = 0; s < 4; s++) {
            bool act = (s == 0) ? a0 : (s == 1) ? a1 : (s == 2) ? a2 : a3;
            if (act) {
                float t0 = __half2float(hv[s][0]) + __half2float(hv[s][1]);
                float t1 = __half2float(hv[s][2]) + __half2float(hv[s][3]);
                float t2 = __half2float(hv[s][4]) + __half2float(hv[s][5]);
                float t3 = __half2float(hv[s][6]) + __half2float(hv[s][7]);
                acc[s] += (t0 + t1) + (t2 + t3);
                ii[s] += 8;
            }
        }
    }
    int curg = -1; float pacc = 0.f;
#pragma unroll
    for (int s = 0; s < 4; ++s) {
        int nu = n0 + s;
        if (nu >= N) break;
        float di = dinv[nu];
        float a = acc[s] + __half2float(h1s[(size_t)nu * HID + lane]);  // self-loop
        float r = di * a;                     // lane f holds agg[f]
        // pack r (fp16) pairs: lane k (k<32) gets {r[2k], r[2k+1]}
        unsigned rhu = (unsigned)__half_as_ushort(__float2half(r));
        unsigned lo = (unsigned)__builtin_amdgcn_ds_bpermute(lane * 8, (int)rhu);
        unsigned hi = (unsigned)__builtin_amdgcn_ds_bpermute(lane * 8 + 4, (int)rhu);
        unsigned pk = (lo & 0xFFFFu) | (hi << 16);
        float o = bias;
#if __has_builtin(__builtin_amdgcn_fdot2)
#pragma unroll
        for (int k2 = 0; k2 < 32; ++k2) {
            unsigned pr = bcast_lane_u(pk, k2);
            o = __builtin_amdgcn_fdot2(__builtin_bit_cast(h2v, pr), wpk[k2], o, false);
        }
#else
#pragma unroll
        for (int k2 = 0; k2 < 32; ++k2) {
            unsigned pr = bcast_lane_u(pk, k2);
            float rx = __half2float(__ushort_as_half((unsigned short)(pr & 0xFFFF)));
            float ry = __half2float(__ushort_as_half((unsigned short)(pr >> 16)));
            o += rx * (float)wpk[k2][0] + ry * (float)wpk[k2][1];
        }
#endif
        float val = tanhf(o);
        int g = batch[nu];
        if (g != curg) {
            if (curg >= 0) atomicAdd(&pooled[curg * FC_DIM + F_IN + HID + lane], pacc);
            pacc = 0.f; curg = g;
        }
        pacc += val;
    }
    if (curg >= 0) atomicAdd(&pooled[curg * FC_DIM + F_IN + HID + lane], pacc);
}

// ---------- fc: fused x-pool (graph-local, coalesced) + matvec ----------
__device__ __forceinline__ int lower_bound_i(const int* b, int n, int v) {
    int lo = 0, hi = n;
    while (lo < hi) { int m = (lo + hi) >> 1; if (b[m] < v) lo = m + 1; else hi = m; }
    return lo;
}

__global__ __launch_bounds__(192) void fc_kernel(
        const float* __restrict__ x, const int* __restrict__ batch,
        const float* __restrict__ pooled, const float* __restrict__ fcW,
        const float* __restrict__ fcb, float* __restrict__ out, int N) {
    __shared__ float p[FC_DIM];
    int g = blockIdx.x, tid = threadIdx.x;
    if (tid < FC_DIM) p[tid] = (tid < F_IN) ? 0.f : pooled[g * FC_DIM + tid];
    __syncthreads();
    int start = lower_bound_i(batch, N, g);
    int end = lower_bound_i(batch, N, g + 1);
    int base = start * F_IN;
    int cnt = (end - start) * F_IN;
    float acc = 0.f;
    for (int i = tid; i < cnt; i += 192) acc += x[base + i];  // stride 192 = 16*12
    atomicAdd(&p[tid % F_IN], acc);
    __syncthreads();
    if (tid < FC_DIM) {
        float o = fcb[tid];
        for (int k = 0; k < FC_DIM; k++) o += p[k] * fcW[tid * FC_DIM + k];
        out[g * FC_DIM + tid] = o;
    }
}

extern "C" void kernel_launch(void* const* d_in, const int* in_sizes, int n_in,
                              void* d_out, int out_size, void* d_ws, size_t ws_size,
                              hipStream_t stream) {
    const float* x   = (const float*)d_in[0];
    const float* W1  = (const float*)d_in[1];
    const float* b1  = (const float*)d_in[2];
    const float* W2  = (const float*)d_in[3];
    const float* b2  = (const float*)d_in[4];
    const float* fcW = (const float*)d_in[5];
    const float* fcb = (const float*)d_in[6];
    const int*   ei  = (const int*)d_in[7];
    const int*   batch = (const int*)d_in[8];
    const int N = in_sizes[8];
    const int E = in_sizes[7] / 2;
    const int* src = ei;
    const int* dst = ei + E;
    const int NB = (N + 63) / 64;

    char* ws = (char*)d_ws;
    size_t off = 0;
    auto alloc = [&](size_t bytes) -> void* {
        void* p = ws + off; off += (bytes + 255) & ~(size_t)255; return p;
    };
    int*    bcnt2  = (int*)alloc((size_t)NB * NPART * 16 * 4);   // padded cursors
    int*    sedge2 = (int*)alloc((size_t)NB * NPART * PCAP * 4); // partitioned bins
    int*    sedgeS = (int*)alloc((size_t)NB * SCAP * 4);         // sorted+padded buckets
    int*    boff   = (int*)alloc((size_t)NB * 65 * 4);
    float*  dinv   = (float*)alloc((size_t)N * 4);
    __half* xs     = (__half*)alloc(((size_t)N + 1) * XS_STRIDE * 2);  // +1 zero row
    __half* h1s    = (__half*)alloc(((size_t)N + 1) * HID * 2);        // +1 zero row
    float*  pooled = (float*)alloc((size_t)N_GRAPHS * FC_DIM * 4);
    float* out = (float*)d_out;

    hipMemsetAsync(bcnt2, 0, (size_t)NB * NPART * 16 * 4, stream);
    hipMemsetAsync(pooled, 0, (size_t)N_GRAPHS * FC_DIM * 4, stream);
    hipMemsetAsync(xs + (size_t)N * XS_STRIDE, 0, XS_STRIDE * 2, stream);   // sentinel row
    hipMemsetAsync(h1s + (size_t)N * HID, 0, HID * 2, stream);              // sentinel row

    count_bin<<<(E / 4 + 255) / 256, 256, 0, stream>>>(src, dst, E, bcnt2, sedge2);
    bucket_sort<<<NB, 256, 0, stream>>>(bcnt2, sedge2, x, sedgeS, boff, dinv, xs, N);
    agg_x_mm1<<<(N + 31) / 32, 256, 0, stream>>>((const __half2*)xs, dinv, boff, sedgeS,
                                                 W1, b1, batch, pooled, h1s, N);
    agg_h_mm2<<<(N + NPB - 1) / NPB, 256, 0, stream>>>(h1s, dinv, boff, sedgeS,
                                                       W2, b2, batch, pooled, N);
    fc_kernel<<<N_GRAPHS, 192, 0, stream>>>(x, batch, pooled, fcW, fcb, out, N);
}

// Round 14
// 220.691 us; speedup vs baseline: 1.4235x; 1.2169x over previous
//
#include <hip/hip_runtime.h>
#include <hip/hip_fp16.h>
#include <math.h>

#define N_GRAPHS 256
#define F_IN 12
#define XS_STRIDE 16
#define HID 64
#define FC_DIM 140
#define SCAP 2304     // sorted+pad8 bucket stride; exact bucket count ~Poisson(1024)
#define NBK_MAX 1564  // max buckets+1 (N=100000 -> 1563 buckets)
#define NSRC 256      // phase-A blocks (= threads in phase-B gather)
#define EPB_MAX 6272  // per-source-block edge slice capacity (E=1.6M -> 6251)

typedef _Float16 h2v __attribute__((ext_vector_type(2)));

__device__ __forceinline__ float bcast_lane(float v, int k) {
    return __uint_as_float(__builtin_amdgcn_readlane(__float_as_uint(v), k));
}
__device__ __forceinline__ unsigned bcast_lane_u(unsigned v, int k) {
    return __builtin_amdgcn_readlane(v, k);
}

// ---------- phase A: block-local counting sort of a contiguous edge slice ----------
// ALL global writes coalesced (full lines) -> no scattered-store write amplification.
__global__ __launch_bounds__(1024) void count_bin(
        const int* __restrict__ src, const int* __restrict__ dst, int E, int epb, int nbk,
        int* __restrict__ eblk, int* __restrict__ hoff) {
    __shared__ int hc[NBK_MAX];    // histogram, then cursors
    __shared__ int hs[NBK_MAX];    // scanned offsets
    __shared__ int esl[EPB_MAX];   // block-locally sorted edges
    __shared__ int wsum[16];
    int k = blockIdx.x, tid = threadIdx.x;
    int base = k * epb;
    int cnt = min(epb, E - base); if (cnt < 0) cnt = 0;
    for (int j = tid; j < nbk; j += 1024) hc[j] = 0;
    __syncthreads();
    int pb[8], pv[8]; int np = 0;
    for (int i = tid; i < cnt; i += 1024) {
        int d = dst[base + i];
        int s = src[base + i];
        int b = d >> 6;
        atomicAdd(&hc[b], 1);
        pb[np] = b; pv[np] = s | ((d & 63) << 20); np++;
    }
    __syncthreads();
    // exclusive scan of hc[0..nbk-1] -> hs (VPT=2)
    int lane = tid & 63, wave = tid >> 6;
    int i0 = tid * 2;
    int v0 = (i0 < nbk) ? hc[i0] : 0;
    int v1 = (i0 + 1 < nbk) ? hc[i0 + 1] : 0;
    int s2 = v0 + v1;
    int incl = s2;
#pragma unroll
    for (int off = 1; off < 64; off <<= 1) {
        int t = __shfl_up(incl, off, 64);
        if (lane >= off) incl += t;
    }
    if (lane == 63) wsum[wave] = incl;
    __syncthreads();
    int woff = 0, tot = 0;
#pragma unroll
    for (int w = 0; w < 16; w++) { int xv = wsum[w]; tot += xv; if (w < wave) woff += xv; }
    int ex = woff + incl - s2;
    if (i0 < nbk) hs[i0] = ex;
    if (i0 + 1 < nbk) hs[i0 + 1] = ex + v0;
    if (tid == 0) hs[nbk] = tot;
    __syncthreads();
    for (int j = tid; j < nbk; j += 1024) hc[j] = hs[j];   // cursors
    __syncthreads();
    for (int q = 0; q < np; ++q) {
        int pos = atomicAdd(&hc[pb[q]], 1);
        esl[pos] = pv[q];
    }
    __syncthreads();
    for (int i = tid; i < cnt; i += 1024) eblk[k * EPB_MAX + i] = esl[i];       // coalesced
    for (int j = tid; j <= nbk; j += 1024) hoff[k * (nbk + 1) + j] = hs[j];     // coalesced
}

// ---------- phase B: per-bucket gather from 256 slices + counting sort + pad-8 + xs ----------
__global__ __launch_bounds__(256) void bucket_sort(
        const int* __restrict__ eblk, const int* __restrict__ hoff,
        const float* __restrict__ x,
        int* __restrict__ sedgeS, int* __restrict__ boff,
        float* __restrict__ dinv, __half* __restrict__ xs, int N, int nbk) {
    __shared__ int eslr[SCAP];
    __shared__ int esl[SCAP];
    __shared__ int cnt[64];
    __shared__ int cur[64];
    __shared__ int startl[64];
    __shared__ int pcl[64];
    __shared__ float dinvl[64];
    __shared__ int wsum4[4];
    int tid = threadIdx.x, b = blockIdx.x;
    int lane = tid & 63, wave = tid >> 6;
    // thread t = source slice t: its run of bucket b
    int o0 = hoff[tid * (nbk + 1) + b];
    int o1 = hoff[tid * (nbk + 1) + b + 1];
    int ck = o1 - o0;
    int incl = ck;
#pragma unroll
    for (int off = 1; off < 64; off <<= 1) {
        int t = __shfl_up(incl, off, 64);
        if (lane >= off) incl += t;
    }
    if (lane == 63) wsum4[wave] = incl;
    __syncthreads();
    int woff = 0, ne = 0;
#pragma unroll
    for (int w = 0; w < 4; w++) { int xv = wsum4[w]; ne += xv; if (w < wave) woff += xv; }
    int gbase = woff + incl - ck;
    const int* seg = eblk + (size_t)tid * EPB_MAX;
    for (int i = 0; i < ck; ++i) {
        int p = gbase + i;
        if (p < SCAP) eslr[p] = seg[o0 + i];
    }
    if (ne > SCAP) ne = SCAP;
    __syncthreads();
    if (tid < 64) cnt[tid] = 0;
    __syncthreads();
    for (int idx = tid; idx < ne; idx += 256) atomicAdd(&cnt[(eslr[idx] >> 20) & 63], 1);
    __syncthreads();
    if (tid < 64) {
        int c = cnt[tid];
        int pc = (c + 7) & ~7;            // pad each node's segment to mult of 8
        int incl2 = pc;
#pragma unroll
        for (int off = 1; off < 64; off <<= 1) {
            int t = __shfl_up(incl2, off, 64);
            if (tid >= off) incl2 += t;
        }
        int st = incl2 - pc;
        startl[tid] = st; cur[tid] = st; pcl[tid] = pc;
        boff[b * 65 + tid] = st;
        if (tid == 63) boff[b * 65 + 64] = incl2;
        float di = rsqrtf((float)(c + 1));  // +1 self-loop (real degree)
        dinvl[tid] = di;
        int node = b * 64 + tid;
        if (node < N) dinv[node] = di;
    }
    __syncthreads();
    for (int idx = tid; idx < ne; idx += 256) {
        int v = eslr[idx];
        int pos = atomicAdd(&cur[(v >> 20) & 63], 1);
        esl[pos] = v & 0xFFFFF;           // src only; dlow implicit in position
    }
    __syncthreads();
    if (tid < 64) {                        // sentinel padding -> zero row N
        int end = startl[tid] + pcl[tid];
        for (int pos = cur[tid]; pos < end; ++pos) esl[pos] = N;
    }
    __syncthreads();
    int netot = startl[63] + pcl[63];
    for (int idx = tid; idx < netot; idx += 256) sedgeS[(size_t)b * SCAP + idx] = esl[idx];
    // fused make_xs for this bucket's nodes
    for (int idx = tid; idx < 64 * XS_STRIDE; idx += 256) {
        int nl = idx >> 4, f = idx & 15;
        int node = b * 64 + nl;
        if (node < N) {
            float v = (f < F_IN) ? dinvl[nl] * x[node * F_IN + f] : 0.f;
            xs[(size_t)node * XS_STRIDE + f] = __float2half(v);
        }
    }
}

// ---------- fused layer-1: 8-lane half2 gather, 16-deep, + mm1 + h1-pool ----------
__global__ __launch_bounds__(256) void agg_x_mm1(
        const __half2* __restrict__ xs2, const float* __restrict__ dinv,
        const int* __restrict__ boff, const int* __restrict__ sedgeS,
        const float* __restrict__ W1, const float* __restrict__ b1,
        const int* __restrict__ batch, float* __restrict__ pooled,
        __half* __restrict__ h1s, int N) {
    int tid = threadIdx.x, wv = tid >> 6, lane = tid & 63;
    int c = lane & 7, gb = lane & 56;  // group base within wave
    float w1c[F_IN];
#pragma unroll
    for (int k = 0; k < F_IN; k++) w1c[k] = W1[k * HID + lane];  // coalesced
    float bias = b1[lane];
    int node = blockIdx.x * 32 + (tid >> 3);
    float ax = 0.f, ay = 0.f, di = 0.f;
    if (node < N) {
        int b = node >> 6, dlow = node & 63;
        di = dinv[node];
        int p0 = boff[b * 65 + dlow], p1 = boff[b * 65 + dlow + 1];
        const int* ep = sedgeS + (size_t)b * SCAP;
        int base = p0;
        for (; base + 16 <= p1; base += 16) {   // 16 gathers in flight
            int ela = ep[base + c];
            int elb = ep[base + 8 + c];
            int ja[8], jb[8];
#pragma unroll
            for (int k = 0; k < 8; k++) ja[k] = __shfl(ela, gb + k, 64);
#pragma unroll
            for (int k = 0; k < 8; k++) jb[k] = __shfl(elb, gb + k, 64);
            float2 va[8], vb[8];
#pragma unroll
            for (int k = 0; k < 8; k++) va[k] = __half22float2(xs2[(size_t)ja[k] * 8 + c]);
#pragma unroll
            for (int k = 0; k < 8; k++) vb[k] = __half22float2(xs2[(size_t)jb[k] * 8 + c]);
#pragma unroll
            for (int k = 0; k < 8; k++) { ax += va[k].x + vb[k].x; ay += va[k].y + vb[k].y; }
        }
        if (base < p1) {                        // remainder: exactly 8 (pad-8)
            int el = ep[base + c];
            int j[8];
#pragma unroll
            for (int k = 0; k < 8; k++) j[k] = __shfl(el, gb + k, 64);
#pragma unroll
            for (int k = 0; k < 8; k++) {
                float2 v = __half22float2(xs2[(size_t)j[k] * 8 + c]);
                ax += v.x; ay += v.y;
            }
        }
        float2 sv = __half22float2(xs2[(size_t)node * 8 + c]);  // self-loop (prescaled)
        ax = di * (ax + sv.x);
        ay = di * (ay + sv.y);
    }
    // epilogue: 8 nodes of this wave; feature k of node q lives in lane q*8+(k>>1)
    int nb0 = blockIdx.x * 32 + wv * 8;
    int curg = -1; float pacc = 0.f;
    for (int q = 0; q < 8; ++q) {
        int nq = nb0 + q;
        if (nq >= N) break;
        float o = bias;
#pragma unroll
        for (int k = 0; k < F_IN; k++) {
            float r = (k & 1) ? bcast_lane(ay, q * 8 + (k >> 1))
                              : bcast_lane(ax, q * 8 + (k >> 1));
            o += r * w1c[k];
        }
        float v = tanhf(o);
        float dq = bcast_lane(di, q * 8);
        h1s[(size_t)nq * HID + lane] = __float2half(dq * v);
        int g = batch[nq];
        if (g != curg) {
            if (curg >= 0) atomicAdd(&pooled[curg * FC_DIM + F_IN + lane], pacc);
            pacc = 0.f; curg = g;
        }
        pacc += v;
    }
    if (curg >= 0) atomicAdd(&pooled[curg * FC_DIM + F_IN + lane], pacc);
}

// ---------- fused layer-2: 4-chain interleaved walk (32 in flight) + dot2 mm2 + pool ----------
#define NPB 16   // nodes per block (4 per wave, 4 interleaved chains)
__global__ __launch_bounds__(256) void agg_h_mm2(
        const __half* __restrict__ h1s, const float* __restrict__ dinv,
        const int* __restrict__ boff, const int* __restrict__ sedgeS,
        const float* __restrict__ W2, const float* __restrict__ b2,
        const int* __restrict__ batch, float* __restrict__ pooled, int N) {
    int tid = threadIdx.x, wv = tid >> 6, lane = tid & 63;
    h2v wpk[32];   // W2 column `lane`, packed pairs (32 VGPRs)
#pragma unroll
    for (int k2 = 0; k2 < 32; k2++) {
        h2v w; w[0] = (_Float16)W2[(2 * k2) * HID + lane];
        w[1] = (_Float16)W2[(2 * k2 + 1) * HID + lane];
        wpk[k2] = w;
    }
    float bias = b2[lane];
    int node0 = blockIdx.x * NPB + wv * 4;
    if (node0 >= N) return;
    int n0 = __builtin_amdgcn_readfirstlane(node0);
    int bu = n0 >> 6, dl0 = n0 & 63;       // 4 consecutive nodes never straddle a bucket
    const int* ep = sedgeS + (size_t)bu * SCAP;
    int bnd[5];
#pragma unroll
    for (int t = 0; t < 5; t++) bnd[t] = boff[bu * 65 + dl0 + t];
    int ii[4]; float acc[4];
#pragma unroll
    for (int s = 0; s < 4; s++) { ii[s] = bnd[s]; acc[s] = 0.f; }
    for (;;) {
        bool a0 = ii[0] < bnd[1], a1 = ii[1] < bnd[2], a2 = ii[2] < bnd[3], a3 = ii[3] < bnd[4];
        if (!(a0 | a1 | a2 | a3)) break;
        __half hv[4][8];
#pragma unroll
        for (int s = 0; s < 4; s++) {
            bool act = (s == 0) ? a0 : (s == 1) ? a1 : (s == 2) ? a2 : a3;
            if (act) {
                int j[8];
#pragma unroll
                for (int k = 0; k < 8; k++) j[k] = ep[ii[s] + k];   // uniform -> s_load
#pragma unroll
                for (int k = 0; k < 8; k++) hv[s][k] = h1s[(size_t)j[k] * HID + lane];
            }
        }
#pragma unroll
        for (int s = 0; s < 4; s++) {
            bool act = (s == 0) ? a0 : (s == 1) ? a1 : (s == 2) ? a2 : a3;
            if (act) {
                float t0 = __half2float(hv[s][0]) + __half2float(hv[s][1]);
                float t1 = __half2float(hv[s][2]) + __half2float(hv[s][3]);
                float t2 = __half2float(hv[s][4]) + __half2float(hv[s][5]);
                float t3 = __half2float(hv[s][6]) + __half2float(hv[s][7]);
                acc[s] += (t0 + t1) + (t2 + t3);
                ii[s] += 8;
            }
        }
    }
    int curg = -1; float pacc = 0.f;
#pragma unroll
    for (int s = 0; s < 4; ++s) {
        int nu = n0 + s;
        if (nu >= N) break;
        float di = dinv[nu];
        float a = acc[s] + __half2float(h1s[(size_t)nu * HID + lane]);  // self-loop
        float r = di * a;                     // lane f holds agg[f]
        // pack r (fp16) pairs: lane k (k<32) gets {r[2k], r[2k+1]}
        unsigned rhu = (unsigned)__half_as_ushort(__float2half(r));
        unsigned lo = (unsigned)__builtin_amdgcn_ds_bpermute(lane * 8, (int)rhu);
        unsigned hi = (unsigned)__builtin_amdgcn_ds_bpermute(lane * 8 + 4, (int)rhu);
        unsigned pk = (lo & 0xFFFFu) | (hi << 16);
        float o = bias;
#if __has_builtin(__builtin_amdgcn_fdot2)
#pragma unroll
        for (int k2 = 0; k2 < 32; ++k2) {
            unsigned pr = bcast_lane_u(pk, k2);
            o = __builtin_amdgcn_fdot2(__builtin_bit_cast(h2v, pr), wpk[k2], o, false);
        }
#else
#pragma unroll
        for (int k2 = 0; k2 < 32; ++k2) {
            unsigned pr = bcast_lane_u(pk, k2);
            float rx = __half2float(__ushort_as_half((unsigned short)(pr & 0xFFFF)));
            float ry = __half2float(__ushort_as_half((unsigned short)(pr >> 16)));
            o += rx * (float)wpk[k2][0] + ry * (float)wpk[k2][1];
        }
#endif
        float val = tanhf(o);
        int g = batch[nu];
        if (g != curg) {
            if (curg >= 0) atomicAdd(&pooled[curg * FC_DIM + F_IN + HID + lane], pacc);
            pacc = 0.f; curg = g;
        }
        pacc += val;
    }
    if (curg >= 0) atomicAdd(&pooled[curg * FC_DIM + F_IN + HID + lane], pacc);
}

// ---------- fc: fused x-pool (graph-local, coalesced) + matvec ----------
__device__ __forceinline__ int lower_bound_i(const int* b, int n, int v) {
    int lo = 0, hi = n;
    while (lo < hi) { int m = (lo + hi) >> 1; if (b[m] < v) lo = m + 1; else hi = m; }
    return lo;
}

__global__ __launch_bounds__(192) void fc_kernel(
        const float* __restrict__ x, const int* __restrict__ batch,
        const float* __restrict__ pooled, const float* __restrict__ fcW,
        const float* __restrict__ fcb, float* __restrict__ out, int N) {
    __shared__ float p[FC_DIM];
    int g = blockIdx.x, tid = threadIdx.x;
    if (tid < FC_DIM) p[tid] = (tid < F_IN) ? 0.f : pooled[g * FC_DIM + tid];
    __syncthreads();
    int start = lower_bound_i(batch, N, g);
    int end = lower_bound_i(batch, N, g + 1);
    int base = start * F_IN;
    int cnt = (end - start) * F_IN;
    float acc = 0.f;
    for (int i = tid; i < cnt; i += 192) acc += x[base + i];  // stride 192 = 16*12
    atomicAdd(&p[tid % F_IN], acc);
    __syncthreads();
    if (tid < FC_DIM) {
        float o = fcb[tid];
        for (int k = 0; k < FC_DIM; k++) o += p[k] * fcW[tid * FC_DIM + k];
        out[g * FC_DIM + tid] = o;
    }
}

extern "C" void kernel_launch(void* const* d_in, const int* in_sizes, int n_in,
                              void* d_out, int out_size, void* d_ws, size_t ws_size,
                              hipStream_t stream) {
    const float* x   = (const float*)d_in[0];
    const float* W1  = (const float*)d_in[1];
    const float* b1  = (const float*)d_in[2];
    const float* W2  = (const float*)d_in[3];
    const float* b2  = (const float*)d_in[4];
    const float* fcW = (const float*)d_in[5];
    const float* fcb = (const float*)d_in[6];
    const int*   ei  = (const int*)d_in[7];
    const int*   batch = (const int*)d_in[8];
    const int N = in_sizes[8];
    const int E = in_sizes[7] / 2;
    const int* src = ei;
    const int* dst = ei + E;
    const int NB = (N + 63) / 64;          // 1563 buckets (NBK_MAX-1)
    const int epb = (E + NSRC - 1) / NSRC; // 6250 <= EPB_MAX

    char* ws = (char*)d_ws;
    size_t off = 0;
    auto alloc = [&](size_t bytes) -> void* {
        void* p = ws + off; off += (bytes + 255) & ~(size_t)255; return p;
    };
    int*    eblk   = (int*)alloc((size_t)NSRC * EPB_MAX * 4);    // block-sorted slices
    int*    hoff   = (int*)alloc((size_t)NSRC * (NB + 1) * 4);   // per-slice bucket offsets
    int*    sedgeS = (int*)alloc((size_t)NB * SCAP * 4);         // sorted+padded buckets
    int*    boff   = (int*)alloc((size_t)NB * 65 * 4);
    float*  dinv   = (float*)alloc((size_t)N * 4);
    __half* xs     = (__half*)alloc(((size_t)N + 1) * XS_STRIDE * 2);  // +1 zero row
    __half* h1s    = (__half*)alloc(((size_t)N + 1) * HID * 2);        // +1 zero row
    float*  pooled = (float*)alloc((size_t)N_GRAPHS * FC_DIM * 4);
    float* out = (float*)d_out;

    hipMemsetAsync(pooled, 0, (size_t)N_GRAPHS * FC_DIM * 4, stream);
    hipMemsetAsync(xs + (size_t)N * XS_STRIDE, 0, XS_STRIDE * 2, stream);   // sentinel row
    hipMemsetAsync(h1s + (size_t)N * HID, 0, HID * 2, stream);              // sentinel row

    count_bin<<<NSRC, 1024, 0, stream>>>(src, dst, E, epb, NB, eblk, hoff);
    bucket_sort<<<NB, 256, 0, stream>>>(eblk, hoff, x, sedgeS, boff, dinv, xs, N, NB);
    agg_x_mm1<<<(N + 31) / 32, 256, 0, stream>>>((const __half2*)xs, dinv, boff, sedgeS,
                                                 W1, b1, batch, pooled, h1s, N);
    agg_h_mm2<<<(N + NPB - 1) / NPB, 256, 0, stream>>>(h1s, dinv, boff, sedgeS,
                                                       W2, b2, batch, pooled, N);
    fc_kernel<<<N_GRAPHS, 192, 0, stream>>>(x, batch, pooled, fcW, fcb, out, N);
}